// Round 9
// baseline (2696.670 us; speedup 1.0000x reference)
//
#include <hip/hip_runtime.h>
#include <math.h>

// WaveNet forward, round 9: split stack fusion by halo + XOR-swizzled LDS.
// - Round-8 postmortem: 6-layer fused stack = 205 us (neutral vs 18x34):
//   halo recompute doubled MFMA work, 69.6KB LDS -> 2 blocks/CU (42% occ),
//   and pad-8 rows gave an 8-bank (~4-way) conflict pattern (2.5e7/dispatch).
// - Fix: stackA = d=1,2,4,8 (halo 15 -> 80-row window, 25% recompute) with
//   swizzled pad-free LDS = 40960 B -> 4 blocks/CU = 100% occupancy at
//   __launch_bounds__(512,8). stackB = d=16,32 (halo 48 -> 112-row window,
//   57344 B -> 2 blocks). Total rows/stack 544 vs 768 (-29% MFMA).
// - LDS swizzle: f16 index = row*128 + (c ^ ((row&7)<<3)) (16B-slot XOR, no
//   pad): fragment reads spread over all 32 banks, 2-way only (free).
// - Singles (d=64..512) and head kept verbatim from round 7/8 (verified).
// - Coop/grid.sync stays deleted (5x regression, round 4).
//
// MFMA 16x16x32_f16: A lane: A[m=lane&15][k=(lane>>4)*8+j]; D lane:
// D[row=(lane>>4)*4+reg][col=lane&15]. Conv A-rows interleaved (a0,b0,a1,b1..)
// so GLU happens in registers. Conv K order: k = tap*128 + c.

#define NB 4
#define WLEN 16384
#define C 128
#define S 256
#define NLAYERS 30
#define TT 64
#define NTB (WLEN / TT)   // 256 tiles per sample
#define XROW 264          // head X row stride (f16): 256 + 8 pad
#define GROW 136          // single-layer tile row stride (f16): 128 + 8 pad

// swizzled f16 index into a pad-free 128-col row (stack kernels only)
#define SX(row, c) ((row) * 128 + ((c) ^ (((row) & 7) << 3)))

typedef _Float16 half8 __attribute__((ext_vector_type(8)));
typedef _Float16 half4 __attribute__((ext_vector_type(4)));
typedef float floatx4 __attribute__((ext_vector_type(4)));

__device__ __forceinline__ float sigmoidf_(float v) {
    return 1.0f / (1.0f + __expf(-v));
}

// ---------------- weight packing (unchanged layouts) ----------------
__global__ void prep_kernel(const float* __restrict__ conv_w,
                            const float* __restrict__ res_w,
                            const float* __restrict__ skip_w,
                            const float* __restrict__ a_w,
                            const float* __restrict__ b_w,
                            const float* __restrict__ conv_b,
                            const float* __restrict__ skip_b,
                            _Float16* __restrict__ cw,
                            _Float16* __restrict__ rsw,
                            _Float16* __restrict__ skw,
                            _Float16* __restrict__ aw,
                            _Float16* __restrict__ bw,
                            float* __restrict__ cbp,
                            float* __restrict__ ssum) {
    const int ncw = NLAYERS * 256 * 256;
    const int nrs = NLAYERS * 128 * 128;
    const int nsk = NLAYERS * 256 * 128;
    const int nab = 256 * 256;
    const int ncb = NLAYERS * 256;
    const int total = ncw + nrs + nsk + nab + nab + ncb + 256;
    for (int idx = blockIdx.x * blockDim.x + threadIdx.x; idx < total;
         idx += gridDim.x * blockDim.x) {
        int i = idx;
        if (i < ncw) {
            int j = i & 7, lane = (i >> 3) & 63, rest = i >> 9;
            int ks = rest & 7; rest >>= 3;
            int mt = rest & 15; int l = rest >> 4;
            int mp = mt * 16 + (lane & 15);
            int orow = (mp >> 1) + (mp & 1) * 128;
            int k = ks * 32 + (lane >> 4) * 8 + j;
            int tap = k >> 7, c = k & 127;
            cw[i] = (_Float16)conv_w[(((size_t)l * 256 + orow) * 128 + c) * 2 + tap];
        } else if (i < ncw + nrs) {
            i -= ncw;
            int j = i & 7, lane = (i >> 3) & 63, rest = i >> 9;
            int ks = rest & 3; rest >>= 2;
            int mt = rest & 7; int l = rest >> 3;
            int m = mt * 16 + (lane & 15);
            int k = ks * 32 + (lane >> 4) * 8 + j;
            rsw[i] = (_Float16)res_w[((size_t)l * 128 + m) * 128 + k];
        } else if (i < ncw + nrs + nsk) {
            i -= ncw + nrs;
            int j = i & 7, lane = (i >> 3) & 63, rest = i >> 9;
            int ks = rest & 3; rest >>= 2;
            int mt = rest & 15; int l = rest >> 4;
            int m = mt * 16 + (lane & 15);
            int k = ks * 32 + (lane >> 4) * 8 + j;
            skw[i] = (_Float16)skip_w[((size_t)l * 256 + m) * 128 + k];
        } else if (i < ncw + nrs + nsk + nab) {
            i -= ncw + nrs + nsk;
            int j = i & 7, lane = (i >> 3) & 63, rest = i >> 9;
            int ks = rest & 7; int mt = rest >> 3;
            aw[i] = (_Float16)a_w[(mt * 16 + (lane & 15)) * 256 + ks * 32 + (lane >> 4) * 8 + j];
        } else if (i < ncw + nrs + nsk + 2 * nab) {
            i -= ncw + nrs + nsk + nab;
            int j = i & 7, lane = (i >> 3) & 63, rest = i >> 9;
            int ks = rest & 7; int mt = rest >> 3;
            bw[i] = (_Float16)b_w[(mt * 16 + (lane & 15)) * 256 + ks * 32 + (lane >> 4) * 8 + j];
        } else if (i < ncw + nrs + nsk + 2 * nab + ncb) {
            i -= ncw + nrs + nsk + 2 * nab;
            int mp = i & 255; int l = i >> 8;
            cbp[i] = conv_b[l * 256 + (mp >> 1) + (mp & 1) * 128];
        } else {
            i -= ncw + nrs + nsk + 2 * nab + ncb;
            float s = 0.f;
            for (int l = 0; l < NLAYERS; ++l) s += skip_b[l * 256 + i];
            ssum[i] = s;
        }
    }
}

// ---------------- front: h0 (f16, [n][t][c]) ----------------
__global__ void front_kernel(const float* __restrict__ x,
                             const float* __restrict__ w_shift,
                             const float* __restrict__ b_shift,
                             _Float16* __restrict__ h) {
    const int n = blockIdx.y;
    const int t = blockIdx.x * 256 + threadIdx.x;
    float x1 = (t >= 1) ? x[n * WLEN + t - 1] : 0.0f;
    float x2 = (t >= 2) ? x[n * WLEN + t - 2] : 0.0f;
    _Float16* hq = h + ((size_t)n * WLEN + t) * 128;
    #pragma unroll
    for (int c0 = 0; c0 < 128; c0 += 8) {
        half8 v;
        #pragma unroll
        for (int j = 0; j < 8; ++j) {
            int c = c0 + j;
            v[j] = (_Float16)fmaf(w_shift[2 * c], x2,
                                  fmaf(w_shift[2 * c + 1], x1, b_shift[c]));
        }
        *(half8*)&hq[c0] = v;
    }
}

// ---------------- fused stack kernel (templated window) ----------------
// Window rows w=0..WR-1 map to t = t0 - HALO + w. Layers d = 2^(E0+j),
// j=0..NL-1. Valid output rows of the last layer start at w = HALO-1 < HALO;
// rows HALO..HALO+63 (= t0..t0+63) are exact. All NT row-tiles computed
// uniformly; tap0 row clamped to >=0 (clamped reads land in garbage rows
// never consumed by valid outputs). LDS pad-free + XOR swizzle (SX).
template <int E0, int NL, int NT, int HALO, bool FIRST>
__global__ __launch_bounds__(512, 8) void stack_kernel(
    const _Float16* __restrict__ h_in, _Float16* __restrict__ h_out,
    _Float16* __restrict__ chunk,
    const _Float16* __restrict__ cw0, const float* __restrict__ cb0,
    const _Float16* __restrict__ rsw0, const float* __restrict__ rb0,
    const _Float16* __restrict__ skw0, const float* __restrict__ ssum) {
    constexpr int WR = NT * 16;
    __shared__ _Float16 SMEM[2 * WR * 128];  // A: 40960 B (4 blk/CU); B: 57344 B (2 blk/CU)
    _Float16* H = SMEM;             // h window, updated in place per layer
    _Float16* G = SMEM + WR * 128;  // gated
    const int n = blockIdx.y, tb = blockIdx.x, t0 = tb * TT;
    const int tid = threadIdx.x;
    const int wave = __builtin_amdgcn_readfirstlane(tid >> 6);  // 0..7
    const int lane = tid & 63, q = lane >> 4, ml = lane & 15;

    // ---- skip accumulator (persistent f32 across the NL layers)
    floatx4 sacc[2][4];
    if (FIRST) {
        #pragma unroll
        for (int mt = 0; mt < 2; ++mt)
            #pragma unroll
            for (int r = 0; r < 4; ++r) {
                float bias = ssum[32 * wave + mt * 16 + q * 4 + r];
                #pragma unroll
                for (int nt = 0; nt < 4; ++nt) sacc[mt][nt][r] = bias;
            }
    } else {
        const _Float16* cp = chunk + ((size_t)n * NTB + tb) * 16384;
        #pragma unroll
        for (int mt = 0; mt < 2; ++mt)
            #pragma unroll
            for (int nt = 0; nt < 4; ++nt) {
                size_t o = (size_t)((((wave * 2 + mt) * 4) + nt) * 64 + lane) * 4;
                half4 v = *(const half4*)&cp[o];
                #pragma unroll
                for (int r = 0; r < 4; ++r) sacc[mt][nt][r] = (float)v[r];
            }
    }

    // ---- stage WR-row window (t0-HALO .. t0+63); t<0 rows = 0 (causal pad)
    const _Float16* hn = h_in + (size_t)n * WLEN * 128;
    #pragma unroll
    for (int it = 0; it < (WR * 16 + 511) / 512; ++it) {
        int idx = it * 512 + tid;
        if (idx < WR * 16) {
            int seg = idx & 15;          // 16B segment (8 f16)
            int w = idx >> 4;            // window row
            int src_t = t0 - HALO + w;
            half8 v = (half8)(_Float16)0.0f;
            if (src_t >= 0)
                v = *(const half8*)&hn[(size_t)src_t * 128 + seg * 8];
            *(half8*)&H[SX(w, seg * 8)] = v;
        }
    }
    __syncthreads();

    const _Float16* cw  = cw0;
    const float*    cb  = cb0;
    const _Float16* rsw = rsw0;
    const float*    rb  = rb0;
    const _Float16* skw = skw0;

    #pragma clang loop unroll(disable)
    for (int j = 0; j < NL; ++j) {
        const int d = 1 << (E0 + j);

        // ---- conv GEMM + GLU over NT row-tiles in passes of <=4
        #pragma unroll
        for (int base = 0; base < NT; base += 4) {
            floatx4 acc[2][4];
            #pragma unroll
            for (int mt = 0; mt < 2; ++mt)
                #pragma unroll
                for (int r = 0; r < 4; ++r) {
                    float bias = cb[32 * wave + mt * 16 + q * 4 + r];
                    #pragma unroll
                    for (int nt = 0; nt < 4; ++nt) acc[mt][nt][r] = bias;
                }
            #pragma unroll
            for (int hp = 0; hp < 2; ++hp) {
                for (int ks = 0; ks < 4; ++ks) {
                    half8 a[2];
                    #pragma unroll
                    for (int mt = 0; mt < 2; ++mt)
                        a[mt] = *(const half8*)&cw[((((2 * wave + mt) * 8) + hp * 4 + ks) * 64 + lane) * 8];
                    #pragma unroll
                    for (int nt = 0; nt < 4; ++nt) {
                        if (base + nt < NT) {
                            int row = (base + nt) * 16 + ml;
                            if (!hp) { row -= d; if (row < 0) row = 0; }  // tap0 = t-d, clamped
                            half8 b = *(const half8*)&H[SX(row, ks * 32 + q * 8)];
                            #pragma unroll
                            for (int mt = 0; mt < 2; ++mt)
                                acc[mt][nt] = __builtin_amdgcn_mfma_f32_16x16x32_f16(a[mt], b, acc[mt][nt], 0, 0, 0);
                        }
                    }
                }
            }
            // GLU -> G (separate buffer from H: no barrier needed before write)
            #pragma unroll
            for (int mt = 0; mt < 2; ++mt)
                #pragma unroll
                for (int nt = 0; nt < 4; ++nt) {
                    if (base + nt < NT) {
                        float g0 = acc[mt][nt][0] * sigmoidf_(acc[mt][nt][1]);
                        float g1 = acc[mt][nt][2] * sigmoidf_(acc[mt][nt][3]);
                        _Float16 p[2] = {(_Float16)g0, (_Float16)g1};
                        *(uint32_t*)&G[SX((base + nt) * 16 + ml, 16 * wave + mt * 8 + 2 * q)] = *(uint32_t*)p;
                    }
                }
        }
        __syncthreads();  // G complete before skip/res read it

        // ---- skip GEMM over the valid tile (window rows HALO..HALO+63) -> sacc
        #pragma unroll
        for (int ks = 0; ks < 4; ++ks) {
            half8 a[2];
            #pragma unroll
            for (int mt = 0; mt < 2; ++mt)
                a[mt] = *(const half8*)&skw[((((2 * wave + mt) * 4) + ks) * 64 + lane) * 8];
            #pragma unroll
            for (int nt = 0; nt < 4; ++nt) {
                half8 b = *(const half8*)&G[SX(HALO + nt * 16 + ml, ks * 32 + q * 8)];
                #pragma unroll
                for (int mt = 0; mt < 2; ++mt)
                    sacc[mt][nt] = __builtin_amdgcn_mfma_f32_16x16x32_f16(a[mt], b, sacc[mt][nt], 0, 0, 0);
            }
        }

        // ---- res GEMM + in-place H update (wave owns 16-channel column block)
        #pragma unroll
        for (int base = 0; base < NT; base += 4) {
            floatx4 racc[4];
            #pragma unroll
            for (int r = 0; r < 4; ++r) {
                float bias = rb[16 * wave + q * 4 + r];
                #pragma unroll
                for (int nt = 0; nt < 4; ++nt) racc[nt][r] = bias;
            }
            #pragma unroll
            for (int ks = 0; ks < 4; ++ks) {
                half8 a = *(const half8*)&rsw[(((wave * 4) + ks) * 64 + lane) * 8];
                #pragma unroll
                for (int nt = 0; nt < 4; ++nt) {
                    if (base + nt < NT) {
                        half8 b = *(const half8*)&G[SX((base + nt) * 16 + ml, ks * 32 + q * 8)];
                        racc[nt] = __builtin_amdgcn_mfma_f32_16x16x32_f16(a, b, racc[nt], 0, 0, 0);
                    }
                }
            }
            #pragma unroll
            for (int nt = 0; nt < 4; ++nt) {
                if (base + nt < NT) {
                    int w = (base + nt) * 16 + ml;
                    int c = 16 * wave + q * 4;
                    half4 hv = *(const half4*)&H[SX(w, c)];
                    half4 o;
                    #pragma unroll
                    for (int r = 0; r < 4; ++r)
                        o[r] = (_Float16)(racc[nt][r] + (float)hv[r]);
                    *(half4*)&H[SX(w, c)] = o;
                }
            }
        }
        __syncthreads();  // H updated before next layer's conv reads

        cw  += 65536; cb += 256; rsw += 16384; rb += 128; skw += 32768;
    }

    // ---- store h_out: window rows HALO..HALO+63 -> t0..t0+63
    _Float16* ho = h_out + (size_t)n * WLEN * 128;
    #pragma unroll
    for (int it = 0; it < 2; ++it) {
        int idx = it * 512 + tid;        // 0..1023
        int seg = idx & 15;
        int w64 = idx >> 4;              // 0..63
        *(half8*)&ho[(size_t)(t0 + w64) * 128 + seg * 8] =
            *(const half8*)&H[SX(HALO + w64, seg * 8)];
    }

    // ---- store skip accumulator (f16 frag-linear, same layout as singles/head)
    {
        _Float16* cp = chunk + ((size_t)n * NTB + tb) * 16384;
        #pragma unroll
        for (int mt = 0; mt < 2; ++mt)
            #pragma unroll
            for (int nt = 0; nt < 4; ++nt) {
                size_t o = (size_t)((((wave * 2 + mt) * 4) + nt) * 64 + lane) * 4;
                half4 v;
                #pragma unroll
                for (int r = 0; r < 4; ++r) v[r] = (_Float16)sacc[mt][nt][r];
                *(half4*)&cp[o] = v;
            }
    }
}

// ---------------- single residual layer (d>=64), 8 waves (round-7) ----------------
__global__ __launch_bounds__(512, 8) void layer_kernel(
    const _Float16* __restrict__ h_in, _Float16* __restrict__ h_out,
    _Float16* __restrict__ chunk,
    const _Float16* __restrict__ cw, const float* __restrict__ cb,
    const _Float16* __restrict__ rsw, const float* __restrict__ rb,
    const _Float16* __restrict__ skw, int d) {
    __shared__ _Float16 SMEM[2 * TT * GROW];  // 34816 B -> 4 blocks/CU
    _Float16* X0 = SMEM;
    _Float16* X1 = SMEM + TT * GROW;
    _Float16* G  = X0;  // alias: tap0 dead after conv reads
    const int n = blockIdx.y, tb = blockIdx.x, t0 = tb * TT;
    const int tid = threadIdx.x;
    const int wave = __builtin_amdgcn_readfirstlane(tid >> 6);  // 0..7
    const int lane = tid & 63, q = lane >> 4, ml = lane & 15;

    const _Float16* hn = h_in + (size_t)n * WLEN * 128;
    #pragma unroll
    for (int it = 0; it < 4; ++it) {
        int idx = it * 512 + tid;
        int seg = idx & 15;
        int rowc = (idx >> 4) & 63;
        int tap = idx >> 10;
        int src_t = t0 + rowc - (tap ? 0 : d);
        half8 v = (half8)(_Float16)0.0f;
        if (src_t >= 0)
            v = *(const half8*)&hn[(size_t)src_t * 128 + seg * 8];
        _Float16* Xb = tap ? X1 : X0;
        *(half8*)&Xb[rowc * GROW + seg * 8] = v;
    }
    __syncthreads();

    floatx4 acc[2][4];
    #pragma unroll
    for (int mt = 0; mt < 2; ++mt)
        #pragma unroll
        for (int r = 0; r < 4; ++r) {
            float bias = cb[32 * wave + mt * 16 + q * 4 + r];
            #pragma unroll
            for (int nt = 0; nt < 4; ++nt) acc[mt][nt][r] = bias;
        }
    #pragma unroll
    for (int hp = 0; hp < 2; ++hp) {
        const _Float16* Xb = hp ? X1 : X0;
        for (int ks = 0; ks < 4; ++ks) {
            half8 a[2];
            #pragma unroll
            for (int mt = 0; mt < 2; ++mt)
                a[mt] = *(const half8*)&cw[((((2 * wave + mt) * 8) + hp * 4 + ks) * 64 + lane) * 8];
            #pragma unroll
            for (int nt = 0; nt < 4; ++nt) {
                half8 b = *(const half8*)&Xb[(nt * 16 + ml) * GROW + ks * 32 + q * 8];
                #pragma unroll
                for (int mt = 0; mt < 2; ++mt)
                    acc[mt][nt] = __builtin_amdgcn_mfma_f32_16x16x32_f16(a[mt], b, acc[mt][nt], 0, 0, 0);
            }
        }
    }
    __syncthreads();

    #pragma unroll
    for (int mt = 0; mt < 2; ++mt)
        #pragma unroll
        for (int nt = 0; nt < 4; ++nt) {
            float g0 = acc[mt][nt][0] * sigmoidf_(acc[mt][nt][1]);
            float g1 = acc[mt][nt][2] * sigmoidf_(acc[mt][nt][3]);
            _Float16 p[2] = {(_Float16)g0, (_Float16)g1};
            *(uint32_t*)&G[(nt * 16 + ml) * GROW + 16 * wave + mt * 8 + 2 * q] = *(uint32_t*)p;
        }
    __syncthreads();

    {
        floatx4 sacc[2][4];
        #pragma unroll
        for (int mt = 0; mt < 2; ++mt)
            #pragma unroll
            for (int nt = 0; nt < 4; ++nt)
                #pragma unroll
                for (int r = 0; r < 4; ++r) sacc[mt][nt][r] = 0.0f;
        #pragma unroll
        for (int ks = 0; ks < 4; ++ks) {
            half8 a[2];
            #pragma unroll
            for (int mt = 0; mt < 2; ++mt)
                a[mt] = *(const half8*)&skw[((((2 * wave + mt) * 4) + ks) * 64 + lane) * 8];
            #pragma unroll
            for (int nt = 0; nt < 4; ++nt) {
                half8 b = *(const half8*)&G[(nt * 16 + ml) * GROW + ks * 32 + q * 8];
                #pragma unroll
                for (int mt = 0; mt < 2; ++mt)
                    sacc[mt][nt] = __builtin_amdgcn_mfma_f32_16x16x32_f16(a[mt], b, sacc[mt][nt], 0, 0, 0);
            }
        }
        _Float16* cp = chunk + ((size_t)n * NTB + tb) * 16384;
        #pragma unroll
        for (int mt = 0; mt < 2; ++mt)
            #pragma unroll
            for (int nt = 0; nt < 4; ++nt) {
                size_t o = (size_t)((((wave * 2 + mt) * 4) + nt) * 64 + lane) * 4;
                half4 v = *(const half4*)&cp[o];
                half4 w;
                #pragma unroll
                for (int r = 0; r < 4; ++r)
                    w[r] = (_Float16)(sacc[mt][nt][r] + (float)v[r]);
                *(half4*)&cp[o] = w;
            }
    }

    {
        floatx4 racc[4];
        #pragma unroll
        for (int r = 0; r < 4; ++r) {
            float bias = rb[16 * wave + q * 4 + r];
            #pragma unroll
            for (int nt = 0; nt < 4; ++nt) racc[nt][r] = bias;
        }
        #pragma unroll
        for (int ks = 0; ks < 4; ++ks) {
            half8 a = *(const half8*)&rsw[(((wave * 4) + ks) * 64 + lane) * 8];
            #pragma unroll
            for (int nt = 0; nt < 4; ++nt) {
                half8 b = *(const half8*)&G[(nt * 16 + ml) * GROW + ks * 32 + q * 8];
                racc[nt] = __builtin_amdgcn_mfma_f32_16x16x32_f16(a, b, racc[nt], 0, 0, 0);
            }
        }
        _Float16* ho = h_out + (size_t)n * WLEN * 128;
        #pragma unroll
        for (int nt = 0; nt < 4; ++nt) {
            int tt = nt * 16 + ml;
            int c = 16 * wave + q * 4;
            half4 hv = *(const half4*)&X1[tt * GROW + c];
            half4 o;
            #pragma unroll
            for (int r = 0; r < 4; ++r)
                o[r] = (_Float16)(racc[nt][r] + (float)hv[r]);
            *(half4*)&ho[(size_t)(t0 + tt) * 128 + c] = o;
        }
    }
}

// ---------------- head (round-7, 8 waves) ----------------
__global__ __launch_bounds__(512, 8) void head_kernel(
    float* __restrict__ out, const _Float16* __restrict__ chunk,
    const _Float16* __restrict__ aw, const float* __restrict__ ab,
    const _Float16* __restrict__ bw, const float* __restrict__ bb) {
    __shared__ _Float16 X[TT * XROW];
    const int n = blockIdx.y, tb = blockIdx.x, t0 = tb * TT;
    const int tid = threadIdx.x;
    const int wave = __builtin_amdgcn_readfirstlane(tid >> 6);
    const int lane = tid & 63, q = lane >> 4, ml = lane & 15;

    {
        const _Float16* cp = chunk + ((size_t)n * NTB + tb) * 16384;
        #pragma unroll
        for (int mt = 0; mt < 2; ++mt)
            #pragma unroll
            for (int nt = 0; nt < 4; ++nt) {
                size_t o = (size_t)((((wave * 2 + mt) * 4) + nt) * 64 + lane) * 4;
                half4 v = *(const half4*)&cp[o];
                half4 z;
                #pragma unroll
                for (int r = 0; r < 4; ++r)
                    z[r] = (_Float16)fmaxf((float)v[r], 0.0f);
                *(half4*)&X[(nt * 16 + ml) * XROW + 32 * wave + mt * 16 + q * 4] = z;
            }
    }
    __syncthreads();

    floatx4 acc[2][4];
    #pragma unroll
    for (int mt = 0; mt < 2; ++mt)
        #pragma unroll
        for (int r = 0; r < 4; ++r) {
            float bias = ab[32 * wave + mt * 16 + q * 4 + r];
            #pragma unroll
            for (int nt = 0; nt < 4; ++nt) acc[mt][nt][r] = bias;
        }
    for (int ks = 0; ks < 8; ++ks) {
        half8 a[2];
        #pragma unroll
        for (int mt = 0; mt < 2; ++mt)
            a[mt] = *(const half8*)&aw[((((2 * wave + mt) * 8) + ks) * 64 + lane) * 8];
        #pragma unroll
        for (int nt = 0; nt < 4; ++nt) {
            half8 b = *(const half8*)&X[(nt * 16 + ml) * XROW + ks * 32 + q * 8];
            #pragma unroll
            for (int mt = 0; mt < 2; ++mt)
                acc[mt][nt] = __builtin_amdgcn_mfma_f32_16x16x32_f16(a[mt], b, acc[mt][nt], 0, 0, 0);
        }
    }
    __syncthreads();
    #pragma unroll
    for (int mt = 0; mt < 2; ++mt)
        #pragma unroll
        for (int nt = 0; nt < 4; ++nt) {
            half4 z;
            #pragma unroll
            for (int r = 0; r < 4; ++r)
                z[r] = (_Float16)fmaxf(acc[mt][nt][r], 0.0f);
            *(half4*)&X[(nt * 16 + ml) * XROW + 32 * wave + mt * 16 + q * 4] = z;
        }
    __syncthreads();

    #pragma unroll
    for (int mt = 0; mt < 2; ++mt)
        #pragma unroll
        for (int r = 0; r < 4; ++r) {
            float bias = bb[32 * wave + mt * 16 + q * 4 + r];
            #pragma unroll
            for (int nt = 0; nt < 4; ++nt) acc[mt][nt][r] = bias;
        }
    for (int ks = 0; ks < 8; ++ks) {
        half8 a[2];
        #pragma unroll
        for (int mt = 0; mt < 2; ++mt)
            a[mt] = *(const half8*)&bw[((((2 * wave + mt) * 8) + ks) * 64 + lane) * 8];
        #pragma unroll
        for (int nt = 0; nt < 4; ++nt) {
            half8 b = *(const half8*)&X[(nt * 16 + ml) * XROW + ks * 32 + q * 8];
            #pragma unroll
            for (int mt = 0; mt < 2; ++mt)
                acc[mt][nt] = __builtin_amdgcn_mfma_f32_16x16x32_f16(a[mt], b, acc[mt][nt], 0, 0, 0);
        }
    }
    float* on = out + (size_t)n * S * WLEN;
    #pragma unroll
    for (int mt = 0; mt < 2; ++mt)
        #pragma unroll
        for (int nt = 0; nt < 4; ++nt)
            #pragma unroll
            for (int r = 0; r < 4; ++r) {
                int o = 32 * wave + mt * 16 + q * 4 + r;
                int tt = t0 + nt * 16 + ml;
                on[(size_t)o * WLEN + tt] = acc[mt][nt][r];
            }
}

extern "C" void kernel_launch(void* const* d_in, const int* in_sizes, int n_in,
                              void* d_out, int out_size, void* d_ws, size_t ws_size,
                              hipStream_t stream) {
    (void)in_sizes; (void)n_in; (void)out_size; (void)ws_size;
    const float* x       = (const float*)d_in[0];
    const float* w_shift = (const float*)d_in[1];
    const float* b_shift = (const float*)d_in[2];
    const float* conv_w  = (const float*)d_in[3];
    const float* conv_b  = (const float*)d_in[4];
    const float* res_w   = (const float*)d_in[5];
    const float* res_b   = (const float*)d_in[6];
    const float* skip_w  = (const float*)d_in[7];
    const float* skip_b  = (const float*)d_in[8];
    const float* a_w     = (const float*)d_in[9];
    const float* a_b     = (const float*)d_in[10];
    const float* b_w     = (const float*)d_in[11];
    const float* b_b     = (const float*)d_in[12];
    float* out = (float*)d_out;

    char* ws = (char*)d_ws;
    size_t off = 0;
    _Float16* hA    = (_Float16*)(ws + off); off += (size_t)NB * WLEN * 128 * 2;
    _Float16* hB    = (_Float16*)(ws + off); off += (size_t)NB * WLEN * 128 * 2;
    _Float16* chunk = (_Float16*)(ws + off); off += (size_t)NB * NTB * 16384 * 2;
    _Float16* cw  = (_Float16*)(ws + off); off += (size_t)NLAYERS * 256 * 256 * 2;
    _Float16* rsw = (_Float16*)(ws + off); off += (size_t)NLAYERS * 128 * 128 * 2;
    _Float16* skw = (_Float16*)(ws + off); off += (size_t)NLAYERS * 256 * 128 * 2;
    _Float16* aw  = (_Float16*)(ws + off); off += 256 * 256 * 2;
    _Float16* bw  = (_Float16*)(ws + off); off += 256 * 256 * 2;
    float* cbp  = (float*)(ws + off); off += (size_t)NLAYERS * 256 * 4;
    float* ssum = (float*)(ws + off); off += 256 * 4;
    // total ~74.3 MB

    prep_kernel<<<512, 256, 0, stream>>>(conv_w, res_w, skip_w, a_w, b_w,
                                         conv_b, skip_b,
                                         cw, rsw, skw, aw, bw, cbp, ssum);
    front_kernel<<<dim3(WLEN / 256, NB), 256, 0, stream>>>(x, w_shift, b_shift, hA);

    const dim3 grid(NTB, NB);
    _Float16* hin = hA;
    _Float16* hout = hB;
    for (int s = 0; s < 3; ++s) {
        const int l0 = s * 10;
        // stackA: layers l0..l0+3 (d=1,2,4,8), 80-row window
        if (s == 0)
            stack_kernel<0, 4, 5, 16, true><<<grid, 512, 0, stream>>>(
                hin, hout, chunk,
                cw + (size_t)l0 * 65536, cbp + l0 * 256,
                rsw + (size_t)l0 * 16384, res_b + l0 * 128,
                skw + (size_t)l0 * 32768, ssum);
        else
            stack_kernel<0, 4, 5, 16, false><<<grid, 512, 0, stream>>>(
                hin, hout, chunk,
                cw + (size_t)l0 * 65536, cbp + l0 * 256,
                rsw + (size_t)l0 * 16384, res_b + l0 * 128,
                skw + (size_t)l0 * 32768, ssum);
        { _Float16* tmp = hin; hin = hout; hout = tmp; }
        // stackB: layers l0+4, l0+5 (d=16,32), 112-row window
        {
            const int lb = l0 + 4;
            stack_kernel<4, 2, 7, 48, false><<<grid, 512, 0, stream>>>(
                hin, hout, chunk,
                cw + (size_t)lb * 65536, cbp + lb * 256,
                rsw + (size_t)lb * 16384, res_b + lb * 128,
                skw + (size_t)lb * 32768, ssum);
            _Float16* tmp = hin; hin = hout; hout = tmp;
        }
        // single layers l0+6 .. l0+9 (d = 64..512)
        for (int jj = 6; jj < 10; ++jj) {
            const int l = l0 + jj;
            const int dil = 1 << jj;
            layer_kernel<<<grid, 512, 0, stream>>>(
                hin, hout, chunk,
                cw + (size_t)l * 65536, cbp + l * 256,
                rsw + (size_t)l * 16384, res_b + l * 128,
                skw + (size_t)l * 32768, dil);
            _Float16* tmp = hin; hin = hout; hout = tmp;
        }
    }

    head_kernel<<<grid, 512, 0, stream>>>(out, chunk, aw, a_b, bw, b_b);
}

// Round 11
// 1403.225 us; speedup vs baseline: 1.9218x; 1.9218x over previous
//
#include <hip/hip_runtime.h>
#include <math.h>

// WaveNet forward, round 10 (resubmit after broker timeout): round-9
// structure with the spill fixed.
// - Round-9 postmortem: __launch_bounds__(512,8) forced <=64 VGPR on the
//   stack kernel -> allocator spilled (VGPR_Count=32, scratch traffic 2.3
//   GB/dispatch, 640 us). Logic was correct (passed). Round-8 proved this
//   register structure fits in 64 VGPRs under (512,4) with zero spill.
// - Fix: stack kernels back to __launch_bounds__(512,4) (128-VGPR budget).
//   If the compiler lands at ~64 VGPRs, HW can still co-resident 4 blocks/CU
//   for stackA (LDS 40960 B); worst case 2. No other changes.
// - Kept from round 9: stackA = d=1,2,4,8 (80-row window, 25% recompute),
//   stackB = d=16,32 (112-row window); pad-free XOR-swizzled LDS
//   (row*128 + (c ^ ((row&7)<<3))) -> 2-way-max bank conflicts.
// - Singles (d=64..512) and head verbatim (round-7, verified).
// - Coop/grid.sync stays deleted (5x regression, round 4).
//
// MFMA 16x16x32_f16: A lane: A[m=lane&15][k=(lane>>4)*8+j]; D lane:
// D[row=(lane>>4)*4+reg][col=lane&15]. Conv A-rows interleaved (a0,b0,a1,b1..)
// so GLU happens in registers. Conv K order: k = tap*128 + c.

#define NB 4
#define WLEN 16384
#define C 128
#define S 256
#define NLAYERS 30
#define TT 64
#define NTB (WLEN / TT)   // 256 tiles per sample
#define XROW 264          // head X row stride (f16): 256 + 8 pad
#define GROW 136          // single-layer tile row stride (f16): 128 + 8 pad

// swizzled f16 index into a pad-free 128-col row (stack kernels only)
#define SX(row, c) ((row) * 128 + ((c) ^ (((row) & 7) << 3)))

typedef _Float16 half8 __attribute__((ext_vector_type(8)));
typedef _Float16 half4 __attribute__((ext_vector_type(4)));
typedef float floatx4 __attribute__((ext_vector_type(4)));

__device__ __forceinline__ float sigmoidf_(float v) {
    return 1.0f / (1.0f + __expf(-v));
}

// ---------------- weight packing (unchanged layouts) ----------------
__global__ void prep_kernel(const float* __restrict__ conv_w,
                            const float* __restrict__ res_w,
                            const float* __restrict__ skip_w,
                            const float* __restrict__ a_w,
                            const float* __restrict__ b_w,
                            const float* __restrict__ conv_b,
                            const float* __restrict__ skip_b,
                            _Float16* __restrict__ cw,
                            _Float16* __restrict__ rsw,
                            _Float16* __restrict__ skw,
                            _Float16* __restrict__ aw,
                            _Float16* __restrict__ bw,
                            float* __restrict__ cbp,
                            float* __restrict__ ssum) {
    const int ncw = NLAYERS * 256 * 256;
    const int nrs = NLAYERS * 128 * 128;
    const int nsk = NLAYERS * 256 * 128;
    const int nab = 256 * 256;
    const int ncb = NLAYERS * 256;
    const int total = ncw + nrs + nsk + nab + nab + ncb + 256;
    for (int idx = blockIdx.x * blockDim.x + threadIdx.x; idx < total;
         idx += gridDim.x * blockDim.x) {
        int i = idx;
        if (i < ncw) {
            int j = i & 7, lane = (i >> 3) & 63, rest = i >> 9;
            int ks = rest & 7; rest >>= 3;
            int mt = rest & 15; int l = rest >> 4;
            int mp = mt * 16 + (lane & 15);
            int orow = (mp >> 1) + (mp & 1) * 128;
            int k = ks * 32 + (lane >> 4) * 8 + j;
            int tap = k >> 7, c = k & 127;
            cw[i] = (_Float16)conv_w[(((size_t)l * 256 + orow) * 128 + c) * 2 + tap];
        } else if (i < ncw + nrs) {
            i -= ncw;
            int j = i & 7, lane = (i >> 3) & 63, rest = i >> 9;
            int ks = rest & 3; rest >>= 2;
            int mt = rest & 7; int l = rest >> 3;
            int m = mt * 16 + (lane & 15);
            int k = ks * 32 + (lane >> 4) * 8 + j;
            rsw[i] = (_Float16)res_w[((size_t)l * 128 + m) * 128 + k];
        } else if (i < ncw + nrs + nsk) {
            i -= ncw + nrs;
            int j = i & 7, lane = (i >> 3) & 63, rest = i >> 9;
            int ks = rest & 3; rest >>= 2;
            int mt = rest & 15; int l = rest >> 4;
            int m = mt * 16 + (lane & 15);
            int k = ks * 32 + (lane >> 4) * 8 + j;
            skw[i] = (_Float16)skip_w[((size_t)l * 256 + m) * 128 + k];
        } else if (i < ncw + nrs + nsk + nab) {
            i -= ncw + nrs + nsk;
            int j = i & 7, lane = (i >> 3) & 63, rest = i >> 9;
            int ks = rest & 7; int mt = rest >> 3;
            aw[i] = (_Float16)a_w[(mt * 16 + (lane & 15)) * 256 + ks * 32 + (lane >> 4) * 8 + j];
        } else if (i < ncw + nrs + nsk + 2 * nab) {
            i -= ncw + nrs + nsk + nab;
            int j = i & 7, lane = (i >> 3) & 63, rest = i >> 9;
            int ks = rest & 7; int mt = rest >> 3;
            bw[i] = (_Float16)b_w[(mt * 16 + (lane & 15)) * 256 + ks * 32 + (lane >> 4) * 8 + j];
        } else if (i < ncw + nrs + nsk + 2 * nab + ncb) {
            i -= ncw + nrs + nsk + 2 * nab;
            int mp = i & 255; int l = i >> 8;
            cbp[i] = conv_b[l * 256 + (mp >> 1) + (mp & 1) * 128];
        } else {
            i -= ncw + nrs + nsk + 2 * nab + ncb;
            float s = 0.f;
            for (int l = 0; l < NLAYERS; ++l) s += skip_b[l * 256 + i];
            ssum[i] = s;
        }
    }
}

// ---------------- front: h0 (f16, [n][t][c]) ----------------
__global__ void front_kernel(const float* __restrict__ x,
                             const float* __restrict__ w_shift,
                             const float* __restrict__ b_shift,
                             _Float16* __restrict__ h) {
    const int n = blockIdx.y;
    const int t = blockIdx.x * 256 + threadIdx.x;
    float x1 = (t >= 1) ? x[n * WLEN + t - 1] : 0.0f;
    float x2 = (t >= 2) ? x[n * WLEN + t - 2] : 0.0f;
    _Float16* hq = h + ((size_t)n * WLEN + t) * 128;
    #pragma unroll
    for (int c0 = 0; c0 < 128; c0 += 8) {
        half8 v;
        #pragma unroll
        for (int j = 0; j < 8; ++j) {
            int c = c0 + j;
            v[j] = (_Float16)fmaf(w_shift[2 * c], x2,
                                  fmaf(w_shift[2 * c + 1], x1, b_shift[c]));
        }
        *(half8*)&hq[c0] = v;
    }
}

// ---------------- fused stack kernel (templated window) ----------------
// Window rows w=0..WR-1 map to t = t0 - HALO + w. Layers d = 2^(E0+j),
// j=0..NL-1. Valid output rows of the last layer start before w = HALO;
// rows HALO..HALO+63 (= t0..t0+63) are exact. All NT row-tiles computed
// uniformly; tap0 row clamped to >=0 (clamped reads land in garbage rows
// never consumed by valid outputs). LDS pad-free + XOR swizzle (SX).
template <int E0, int NL, int NT, int HALO, bool FIRST>
__global__ __launch_bounds__(512, 4) void stack_kernel(
    const _Float16* __restrict__ h_in, _Float16* __restrict__ h_out,
    _Float16* __restrict__ chunk,
    const _Float16* __restrict__ cw0, const float* __restrict__ cb0,
    const _Float16* __restrict__ rsw0, const float* __restrict__ rb0,
    const _Float16* __restrict__ skw0, const float* __restrict__ ssum) {
    constexpr int WR = NT * 16;
    __shared__ _Float16 SMEM[2 * WR * 128];  // A: 40960 B; B: 57344 B
    _Float16* H = SMEM;             // h window, updated in place per layer
    _Float16* G = SMEM + WR * 128;  // gated
    const int n = blockIdx.y, tb = blockIdx.x, t0 = tb * TT;
    const int tid = threadIdx.x;
    const int wave = __builtin_amdgcn_readfirstlane(tid >> 6);  // 0..7
    const int lane = tid & 63, q = lane >> 4, ml = lane & 15;

    // ---- skip accumulator (persistent f32 across the NL layers)
    floatx4 sacc[2][4];
    if (FIRST) {
        #pragma unroll
        for (int mt = 0; mt < 2; ++mt)
            #pragma unroll
            for (int r = 0; r < 4; ++r) {
                float bias = ssum[32 * wave + mt * 16 + q * 4 + r];
                #pragma unroll
                for (int nt = 0; nt < 4; ++nt) sacc[mt][nt][r] = bias;
            }
    } else {
        const _Float16* cp = chunk + ((size_t)n * NTB + tb) * 16384;
        #pragma unroll
        for (int mt = 0; mt < 2; ++mt)
            #pragma unroll
            for (int nt = 0; nt < 4; ++nt) {
                size_t o = (size_t)((((wave * 2 + mt) * 4) + nt) * 64 + lane) * 4;
                half4 v = *(const half4*)&cp[o];
                #pragma unroll
                for (int r = 0; r < 4; ++r) sacc[mt][nt][r] = (float)v[r];
            }
    }

    // ---- stage WR-row window (t0-HALO .. t0+63); t<0 rows = 0 (causal pad)
    const _Float16* hn = h_in + (size_t)n * WLEN * 128;
    #pragma unroll
    for (int it = 0; it < (WR * 16 + 511) / 512; ++it) {
        int idx = it * 512 + tid;
        if (idx < WR * 16) {
            int seg = idx & 15;          // 16B segment (8 f16)
            int w = idx >> 4;            // window row
            int src_t = t0 - HALO + w;
            half8 v = (half8)(_Float16)0.0f;
            if (src_t >= 0)
                v = *(const half8*)&hn[(size_t)src_t * 128 + seg * 8];
            *(half8*)&H[SX(w, seg * 8)] = v;
        }
    }
    __syncthreads();

    const _Float16* cw  = cw0;
    const float*    cb  = cb0;
    const _Float16* rsw = rsw0;
    const float*    rb  = rb0;
    const _Float16* skw = skw0;

    #pragma clang loop unroll(disable)
    for (int j = 0; j < NL; ++j) {
        const int d = 1 << (E0 + j);

        // ---- conv GEMM + GLU over NT row-tiles in passes of <=4
        #pragma unroll
        for (int base = 0; base < NT; base += 4) {
            floatx4 acc[2][4];
            #pragma unroll
            for (int mt = 0; mt < 2; ++mt)
                #pragma unroll
                for (int r = 0; r < 4; ++r) {
                    float bias = cb[32 * wave + mt * 16 + q * 4 + r];
                    #pragma unroll
                    for (int nt = 0; nt < 4; ++nt) acc[mt][nt][r] = bias;
                }
            #pragma unroll
            for (int hp = 0; hp < 2; ++hp) {
                for (int ks = 0; ks < 4; ++ks) {
                    half8 a[2];
                    #pragma unroll
                    for (int mt = 0; mt < 2; ++mt)
                        a[mt] = *(const half8*)&cw[((((2 * wave + mt) * 8) + hp * 4 + ks) * 64 + lane) * 8];
                    #pragma unroll
                    for (int nt = 0; nt < 4; ++nt) {
                        if (base + nt < NT) {
                            int row = (base + nt) * 16 + ml;
                            if (!hp) { row -= d; if (row < 0) row = 0; }  // tap0 = t-d, clamped
                            half8 b = *(const half8*)&H[SX(row, ks * 32 + q * 8)];
                            #pragma unroll
                            for (int mt = 0; mt < 2; ++mt)
                                acc[mt][nt] = __builtin_amdgcn_mfma_f32_16x16x32_f16(a[mt], b, acc[mt][nt], 0, 0, 0);
                        }
                    }
                }
            }
            // GLU -> G (separate buffer from H: no barrier needed before write)
            #pragma unroll
            for (int mt = 0; mt < 2; ++mt)
                #pragma unroll
                for (int nt = 0; nt < 4; ++nt) {
                    if (base + nt < NT) {
                        float g0 = acc[mt][nt][0] * sigmoidf_(acc[mt][nt][1]);
                        float g1 = acc[mt][nt][2] * sigmoidf_(acc[mt][nt][3]);
                        _Float16 p[2] = {(_Float16)g0, (_Float16)g1};
                        *(uint32_t*)&G[SX((base + nt) * 16 + ml, 16 * wave + mt * 8 + 2 * q)] = *(uint32_t*)p;
                    }
                }
        }
        __syncthreads();  // G complete before skip/res read it

        // ---- skip GEMM over the valid tile (window rows HALO..HALO+63) -> sacc
        #pragma unroll
        for (int ks = 0; ks < 4; ++ks) {
            half8 a[2];
            #pragma unroll
            for (int mt = 0; mt < 2; ++mt)
                a[mt] = *(const half8*)&skw[((((2 * wave + mt) * 4) + ks) * 64 + lane) * 8];
            #pragma unroll
            for (int nt = 0; nt < 4; ++nt) {
                half8 b = *(const half8*)&G[SX(HALO + nt * 16 + ml, ks * 32 + q * 8)];
                #pragma unroll
                for (int mt = 0; mt < 2; ++mt)
                    sacc[mt][nt] = __builtin_amdgcn_mfma_f32_16x16x32_f16(a[mt], b, sacc[mt][nt], 0, 0, 0);
            }
        }

        // ---- res GEMM + in-place H update (wave owns 16-channel column block)
        #pragma unroll
        for (int base = 0; base < NT; base += 4) {
            floatx4 racc[4];
            #pragma unroll
            for (int r = 0; r < 4; ++r) {
                float bias = rb[16 * wave + q * 4 + r];
                #pragma unroll
                for (int nt = 0; nt < 4; ++nt) racc[nt][r] = bias;
            }
            #pragma unroll
            for (int ks = 0; ks < 4; ++ks) {
                half8 a = *(const half8*)&rsw[(((wave * 4) + ks) * 64 + lane) * 8];
                #pragma unroll
                for (int nt = 0; nt < 4; ++nt) {
                    if (base + nt < NT) {
                        half8 b = *(const half8*)&G[SX((base + nt) * 16 + ml, ks * 32 + q * 8)];
                        racc[nt] = __builtin_amdgcn_mfma_f32_16x16x32_f16(a, b, racc[nt], 0, 0, 0);
                    }
                }
            }
            #pragma unroll
            for (int nt = 0; nt < 4; ++nt) {
                if (base + nt < NT) {
                    int w = (base + nt) * 16 + ml;
                    int c = 16 * wave + q * 4;
                    half4 hv = *(const half4*)&H[SX(w, c)];
                    half4 o;
                    #pragma unroll
                    for (int r = 0; r < 4; ++r)
                        o[r] = (_Float16)(racc[nt][r] + (float)hv[r]);
                    *(half4*)&H[SX(w, c)] = o;
                }
            }
        }
        __syncthreads();  // H updated before next layer's conv reads

        cw  += 65536; cb += 256; rsw += 16384; rb += 128; skw += 32768;
    }

    // ---- store h_out: window rows HALO..HALO+63 -> t0..t0+63
    _Float16* ho = h_out + (size_t)n * WLEN * 128;
    #pragma unroll
    for (int it = 0; it < 2; ++it) {
        int idx = it * 512 + tid;        // 0..1023
        int seg = idx & 15;
        int w64 = idx >> 4;              // 0..63
        *(half8*)&ho[(size_t)(t0 + w64) * 128 + seg * 8] =
            *(const half8*)&H[SX(HALO + w64, seg * 8)];
    }

    // ---- store skip accumulator (f16 frag-linear, same layout as singles/head)
    {
        _Float16* cp = chunk + ((size_t)n * NTB + tb) * 16384;
        #pragma unroll
        for (int mt = 0; mt < 2; ++mt)
            #pragma unroll
            for (int nt = 0; nt < 4; ++nt) {
                size_t o = (size_t)((((wave * 2 + mt) * 4) + nt) * 64 + lane) * 4;
                half4 v;
                #pragma unroll
                for (int r = 0; r < 4; ++r) v[r] = (_Float16)sacc[mt][nt][r];
                *(half4*)&cp[o] = v;
            }
    }
}

// ---------------- single residual layer (d>=64), 8 waves (round-7) ----------------
__global__ __launch_bounds__(512, 8) void layer_kernel(
    const _Float16* __restrict__ h_in, _Float16* __restrict__ h_out,
    _Float16* __restrict__ chunk,
    const _Float16* __restrict__ cw, const float* __restrict__ cb,
    const _Float16* __restrict__ rsw, const float* __restrict__ rb,
    const _Float16* __restrict__ skw, int d) {
    __shared__ _Float16 SMEM[2 * TT * GROW];  // 34816 B -> 4 blocks/CU
    _Float16* X0 = SMEM;
    _Float16* X1 = SMEM + TT * GROW;
    _Float16* G  = X0;  // alias: tap0 dead after conv reads
    const int n = blockIdx.y, tb = blockIdx.x, t0 = tb * TT;
    const int tid = threadIdx.x;
    const int wave = __builtin_amdgcn_readfirstlane(tid >> 6);  // 0..7
    const int lane = tid & 63, q = lane >> 4, ml = lane & 15;

    const _Float16* hn = h_in + (size_t)n * WLEN * 128;
    #pragma unroll
    for (int it = 0; it < 4; ++it) {
        int idx = it * 512 + tid;
        int seg = idx & 15;
        int rowc = (idx >> 4) & 63;
        int tap = idx >> 10;
        int src_t = t0 + rowc - (tap ? 0 : d);
        half8 v = (half8)(_Float16)0.0f;
        if (src_t >= 0)
            v = *(const half8*)&hn[(size_t)src_t * 128 + seg * 8];
        _Float16* Xb = tap ? X1 : X0;
        *(half8*)&Xb[rowc * GROW + seg * 8] = v;
    }
    __syncthreads();

    floatx4 acc[2][4];
    #pragma unroll
    for (int mt = 0; mt < 2; ++mt)
        #pragma unroll
        for (int r = 0; r < 4; ++r) {
            float bias = cb[32 * wave + mt * 16 + q * 4 + r];
            #pragma unroll
            for (int nt = 0; nt < 4; ++nt) acc[mt][nt][r] = bias;
        }
    #pragma unroll
    for (int hp = 0; hp < 2; ++hp) {
        const _Float16* Xb = hp ? X1 : X0;
        for (int ks = 0; ks < 4; ++ks) {
            half8 a[2];
            #pragma unroll
            for (int mt = 0; mt < 2; ++mt)
                a[mt] = *(const half8*)&cw[((((2 * wave + mt) * 8) + hp * 4 + ks) * 64 + lane) * 8];
            #pragma unroll
            for (int nt = 0; nt < 4; ++nt) {
                half8 b = *(const half8*)&Xb[(nt * 16 + ml) * GROW + ks * 32 + q * 8];
                #pragma unroll
                for (int mt = 0; mt < 2; ++mt)
                    acc[mt][nt] = __builtin_amdgcn_mfma_f32_16x16x32_f16(a[mt], b, acc[mt][nt], 0, 0, 0);
            }
        }
    }
    __syncthreads();

    #pragma unroll
    for (int mt = 0; mt < 2; ++mt)
        #pragma unroll
        for (int nt = 0; nt < 4; ++nt) {
            float g0 = acc[mt][nt][0] * sigmoidf_(acc[mt][nt][1]);
            float g1 = acc[mt][nt][2] * sigmoidf_(acc[mt][nt][3]);
            _Float16 p[2] = {(_Float16)g0, (_Float16)g1};
            *(uint32_t*)&G[(nt * 16 + ml) * GROW + 16 * wave + mt * 8 + 2 * q] = *(uint32_t*)p;
        }
    __syncthreads();

    {
        floatx4 sacc[2][4];
        #pragma unroll
        for (int mt = 0; mt < 2; ++mt)
            #pragma unroll
            for (int nt = 0; nt < 4; ++nt)
                #pragma unroll
                for (int r = 0; r < 4; ++r) sacc[mt][nt][r] = 0.0f;
        #pragma unroll
        for (int ks = 0; ks < 4; ++ks) {
            half8 a[2];
            #pragma unroll
            for (int mt = 0; mt < 2; ++mt)
                a[mt] = *(const half8*)&skw[((((2 * wave + mt) * 4) + ks) * 64 + lane) * 8];
            #pragma unroll
            for (int nt = 0; nt < 4; ++nt) {
                half8 b = *(const half8*)&G[(nt * 16 + ml) * GROW + ks * 32 + q * 8];
                #pragma unroll
                for (int mt = 0; mt < 2; ++mt)
                    sacc[mt][nt] = __builtin_amdgcn_mfma_f32_16x16x32_f16(a[mt], b, sacc[mt][nt], 0, 0, 0);
            }
        }
        _Float16* cp = chunk + ((size_t)n * NTB + tb) * 16384;
        #pragma unroll
        for (int mt = 0; mt < 2; ++mt)
            #pragma unroll
            for (int nt = 0; nt < 4; ++nt) {
                size_t o = (size_t)((((wave * 2 + mt) * 4) + nt) * 64 + lane) * 4;
                half4 v = *(const half4*)&cp[o];
                half4 w;
                #pragma unroll
                for (int r = 0; r < 4; ++r)
                    w[r] = (_Float16)(sacc[mt][nt][r] + (float)v[r]);
                *(half4*)&cp[o] = w;
            }
    }

    {
        floatx4 racc[4];
        #pragma unroll
        for (int r = 0; r < 4; ++r) {
            float bias = rb[16 * wave + q * 4 + r];
            #pragma unroll
            for (int nt = 0; nt < 4; ++nt) racc[nt][r] = bias;
        }
        #pragma unroll
        for (int ks = 0; ks < 4; ++ks) {
            half8 a = *(const half8*)&rsw[(((wave * 4) + ks) * 64 + lane) * 8];
            #pragma unroll
            for (int nt = 0; nt < 4; ++nt) {
                half8 b = *(const half8*)&G[(nt * 16 + ml) * GROW + ks * 32 + q * 8];
                racc[nt] = __builtin_amdgcn_mfma_f32_16x16x32_f16(a, b, racc[nt], 0, 0, 0);
            }
        }
        _Float16* ho = h_out + (size_t)n * WLEN * 128;
        #pragma unroll
        for (int nt = 0; nt < 4; ++nt) {
            int tt = nt * 16 + ml;
            int c = 16 * wave + q * 4;
            half4 hv = *(const half4*)&X1[tt * GROW + c];
            half4 o;
            #pragma unroll
            for (int r = 0; r < 4; ++r)
                o[r] = (_Float16)(racc[nt][r] + (float)hv[r]);
            *(half4*)&ho[(size_t)(t0 + tt) * 128 + c] = o;
        }
    }
}

// ---------------- head (round-7, 8 waves) ----------------
__global__ __launch_bounds__(512, 8) void head_kernel(
    float* __restrict__ out, const _Float16* __restrict__ chunk,
    const _Float16* __restrict__ aw, const float* __restrict__ ab,
    const _Float16* __restrict__ bw, const float* __restrict__ bb) {
    __shared__ _Float16 X[TT * XROW];
    const int n = blockIdx.y, tb = blockIdx.x, t0 = tb * TT;
    const int tid = threadIdx.x;
    const int wave = __builtin_amdgcn_readfirstlane(tid >> 6);
    const int lane = tid & 63, q = lane >> 4, ml = lane & 15;

    {
        const _Float16* cp = chunk + ((size_t)n * NTB + tb) * 16384;
        #pragma unroll
        for (int mt = 0; mt < 2; ++mt)
            #pragma unroll
            for (int nt = 0; nt < 4; ++nt) {
                size_t o = (size_t)((((wave * 2 + mt) * 4) + nt) * 64 + lane) * 4;
                half4 v = *(const half4*)&cp[o];
                half4 z;
                #pragma unroll
                for (int r = 0; r < 4; ++r)
                    z[r] = (_Float16)fmaxf((float)v[r], 0.0f);
                *(half4*)&X[(nt * 16 + ml) * XROW + 32 * wave + mt * 16 + q * 4] = z;
            }
    }
    __syncthreads();

    floatx4 acc[2][4];
    #pragma unroll
    for (int mt = 0; mt < 2; ++mt)
        #pragma unroll
        for (int r = 0; r < 4; ++r) {
            float bias = ab[32 * wave + mt * 16 + q * 4 + r];
            #pragma unroll
            for (int nt = 0; nt < 4; ++nt) acc[mt][nt][r] = bias;
        }
    for (int ks = 0; ks < 8; ++ks) {
        half8 a[2];
        #pragma unroll
        for (int mt = 0; mt < 2; ++mt)
            a[mt] = *(const half8*)&aw[((((2 * wave + mt) * 8) + ks) * 64 + lane) * 8];
        #pragma unroll
        for (int nt = 0; nt < 4; ++nt) {
            half8 b = *(const half8*)&X[(nt * 16 + ml) * XROW + ks * 32 + q * 8];
            #pragma unroll
            for (int mt = 0; mt < 2; ++mt)
                acc[mt][nt] = __builtin_amdgcn_mfma_f32_16x16x32_f16(a[mt], b, acc[mt][nt], 0, 0, 0);
        }
    }
    __syncthreads();
    #pragma unroll
    for (int mt = 0; mt < 2; ++mt)
        #pragma unroll
        for (int nt = 0; nt < 4; ++nt) {
            half4 z;
            #pragma unroll
            for (int r = 0; r < 4; ++r)
                z[r] = (_Float16)fmaxf(acc[mt][nt][r], 0.0f);
            *(half4*)&X[(nt * 16 + ml) * XROW + 32 * wave + mt * 16 + q * 4] = z;
        }
    __syncthreads();

    #pragma unroll
    for (int mt = 0; mt < 2; ++mt)
        #pragma unroll
        for (int r = 0; r < 4; ++r) {
            float bias = bb[32 * wave + mt * 16 + q * 4 + r];
            #pragma unroll
            for (int nt = 0; nt < 4; ++nt) acc[mt][nt][r] = bias;
        }
    for (int ks = 0; ks < 8; ++ks) {
        half8 a[2];
        #pragma unroll
        for (int mt = 0; mt < 2; ++mt)
            a[mt] = *(const half8*)&bw[((((2 * wave + mt) * 8) + ks) * 64 + lane) * 8];
        #pragma unroll
        for (int nt = 0; nt < 4; ++nt) {
            half8 b = *(const half8*)&X[(nt * 16 + ml) * XROW + ks * 32 + q * 8];
            #pragma unroll
            for (int mt = 0; mt < 2; ++mt)
                acc[mt][nt] = __builtin_amdgcn_mfma_f32_16x16x32_f16(a[mt], b, acc[mt][nt], 0, 0, 0);
        }
    }
    float* on = out + (size_t)n * S * WLEN;
    #pragma unroll
    for (int mt = 0; mt < 2; ++mt)
        #pragma unroll
        for (int nt = 0; nt < 4; ++nt)
            #pragma unroll
            for (int r = 0; r < 4; ++r) {
                int o = 32 * wave + mt * 16 + q * 4 + r;
                int tt = t0 + nt * 16 + ml;
                on[(size_t)o * WLEN + tt] = acc[mt][nt][r];
            }
}

extern "C" void kernel_launch(void* const* d_in, const int* in_sizes, int n_in,
                              void* d_out, int out_size, void* d_ws, size_t ws_size,
                              hipStream_t stream) {
    (void)in_sizes; (void)n_in; (void)out_size; (void)ws_size;
    const float* x       = (const float*)d_in[0];
    const float* w_shift = (const float*)d_in[1];
    const float* b_shift = (const float*)d_in[2];
    const float* conv_w  = (const float*)d_in[3];
    const float* conv_b  = (const float*)d_in[4];
    const float* res_w   = (const float*)d_in[5];
    const float* res_b   = (const float*)d_in[6];
    const float* skip_w  = (const float*)d_in[7];
    const float* skip_b  = (const float*)d_in[8];
    const float* a_w     = (const float*)d_in[9];
    const float* a_b     = (const float*)d_in[10];
    const float* b_w     = (const float*)d_in[11];
    const float* b_b     = (const float*)d_in[12];
    float* out = (float*)d_out;

    char* ws = (char*)d_ws;
    size_t off = 0;
    _Float16* hA    = (_Float16*)(ws + off); off += (size_t)NB * WLEN * 128 * 2;
    _Float16* hB    = (_Float16*)(ws + off); off += (size_t)NB * WLEN * 128 * 2;
    _Float16* chunk = (_Float16*)(ws + off); off += (size_t)NB * NTB * 16384 * 2;
    _Float16* cw  = (_Float16*)(ws + off); off += (size_t)NLAYERS * 256 * 256 * 2;
    _Float16* rsw = (_Float16*)(ws + off); off += (size_t)NLAYERS * 128 * 128 * 2;
    _Float16* skw = (_Float16*)(ws + off); off += (size_t)NLAYERS * 256 * 128 * 2;
    _Float16* aw  = (_Float16*)(ws + off); off += 256 * 256 * 2;
    _Float16* bw  = (_Float16*)(ws + off); off += 256 * 256 * 2;
    float* cbp  = (float*)(ws + off); off += (size_t)NLAYERS * 256 * 4;
    float* ssum = (float*)(ws + off); off += 256 * 4;
    // total ~74.3 MB

    prep_kernel<<<512, 256, 0, stream>>>(conv_w, res_w, skip_w, a_w, b_w,
                                         conv_b, skip_b,
                                         cw, rsw, skw, aw, bw, cbp, ssum);
    front_kernel<<<dim3(WLEN / 256, NB), 256, 0, stream>>>(x, w_shift, b_shift, hA);

    const dim3 grid(NTB, NB);
    _Float16* hin = hA;
    _Float16* hout = hB;
    for (int s = 0; s < 3; ++s) {
        const int l0 = s * 10;
        // stackA: layers l0..l0+3 (d=1,2,4,8), 80-row window
        if (s == 0)
            stack_kernel<0, 4, 5, 16, true><<<grid, 512, 0, stream>>>(
                hin, hout, chunk,
                cw + (size_t)l0 * 65536, cbp + l0 * 256,
                rsw + (size_t)l0 * 16384, res_b + l0 * 128,
                skw + (size_t)l0 * 32768, ssum);
        else
            stack_kernel<0, 4, 5, 16, false><<<grid, 512, 0, stream>>>(
                hin, hout, chunk,
                cw + (size_t)l0 * 65536, cbp + l0 * 256,
                rsw + (size_t)l0 * 16384, res_b + l0 * 128,
                skw + (size_t)l0 * 32768, ssum);
        { _Float16* tmp = hin; hin = hout; hout = tmp; }
        // stackB: layers l0+4, l0+5 (d=16,32), 112-row window
        {
            const int lb = l0 + 4;
            stack_kernel<4, 2, 7, 48, false><<<grid, 512, 0, stream>>>(
                hin, hout, chunk,
                cw + (size_t)lb * 65536, cbp + lb * 256,
                rsw + (size_t)lb * 16384, res_b + lb * 128,
                skw + (size_t)lb * 32768, ssum);
            _Float16* tmp = hin; hin = hout; hout = tmp;
        }
        // single layers l0+6 .. l0+9 (d = 64..512)
        for (int jj = 6; jj < 10; ++jj) {
            const int l = l0 + jj;
            const int dil = 1 << jj;
            layer_kernel<<<grid, 512, 0, stream>>>(
                hin, hout, chunk,
                cw + (size_t)l * 65536, cbp + l * 256,
                rsw + (size_t)l * 16384, res_b + l * 128,
                skw + (size_t)l * 32768, dil);
            _Float16* tmp = hin; hin = hout; hout = tmp;
        }
    }

    head_kernel<<<grid, 512, 0, stream>>>(out, chunk, aw, a_b, bw, b_b);
}

// Round 13
// 1114.509 us; speedup vs baseline: 2.4196x; 1.2591x over previous
//
#include <hip/hip_runtime.h>
#include <math.h>

// WaveNet forward, round 11 (resubmit after broker timeout): stop the
// allocator from spilling for occupancy.
// - Round-10 postmortem: __launch_bounds__(512,4) sets only the MIN waves/EU;
//   LDS=40960 permits 4 blocks/CU, so the allocator chased 8 waves/EU, squeezed
//   to 64 VGPRs and spilled sacc/acc (VGPR_Count=64, FETCH 279MB / WRITE 430MB
//   of scratch traffic, 190-214 us/dispatch). Also: bank-conflict count was
//   exactly proportional to round-8's per-row-layer rate -> SX swizzle was
//   neutral; conflicts were never the lever.
// - Fix (one variable): __attribute__((amdgpu_waves_per_eu(2,4))) on the stack
//   kernels caps the occupancy target at 4 waves/EU -> firm 128-VGPR budget ->
//   no spill. 2 blocks/CU x 8 waves = 4 waves/EU is what LDS+VGPR then carry.
// - Everything else byte-identical to round 10 (which PASSED): stackA =
//   d=1,2,4,8 (80-row window, 25% recompute), stackB = d=16,32 (112-row
//   window); pad-free XOR LDS; singles (d>=64) + head verbatim round-7.
// - Coop/grid.sync stays deleted (5x regression, round 4).
//
// MFMA 16x16x32_f16: A lane: A[m=lane&15][k=(lane>>4)*8+j]; D lane:
// D[row=(lane>>4)*4+reg][col=lane&15]. Conv A-rows interleaved (a0,b0,a1,b1..)
// so GLU happens in registers. Conv K order: k = tap*128 + c.

#define NB 4
#define WLEN 16384
#define C 128
#define S 256
#define NLAYERS 30
#define TT 64
#define NTB (WLEN / TT)   // 256 tiles per sample
#define XROW 264          // head X row stride (f16): 256 + 8 pad
#define GROW 136          // single-layer tile row stride (f16): 128 + 8 pad

// swizzled f16 index into a pad-free 128-col row (stack kernels only)
#define SX(row, c) ((row) * 128 + ((c) ^ (((row) & 7) << 3)))

typedef _Float16 half8 __attribute__((ext_vector_type(8)));
typedef _Float16 half4 __attribute__((ext_vector_type(4)));
typedef float floatx4 __attribute__((ext_vector_type(4)));

__device__ __forceinline__ float sigmoidf_(float v) {
    return 1.0f / (1.0f + __expf(-v));
}

// ---------------- weight packing (unchanged layouts) ----------------
__global__ void prep_kernel(const float* __restrict__ conv_w,
                            const float* __restrict__ res_w,
                            const float* __restrict__ skip_w,
                            const float* __restrict__ a_w,
                            const float* __restrict__ b_w,
                            const float* __restrict__ conv_b,
                            const float* __restrict__ skip_b,
                            _Float16* __restrict__ cw,
                            _Float16* __restrict__ rsw,
                            _Float16* __restrict__ skw,
                            _Float16* __restrict__ aw,
                            _Float16* __restrict__ bw,
                            float* __restrict__ cbp,
                            float* __restrict__ ssum) {
    const int ncw = NLAYERS * 256 * 256;
    const int nrs = NLAYERS * 128 * 128;
    const int nsk = NLAYERS * 256 * 128;
    const int nab = 256 * 256;
    const int ncb = NLAYERS * 256;
    const int total = ncw + nrs + nsk + nab + nab + ncb + 256;
    for (int idx = blockIdx.x * blockDim.x + threadIdx.x; idx < total;
         idx += gridDim.x * blockDim.x) {
        int i = idx;
        if (i < ncw) {
            int j = i & 7, lane = (i >> 3) & 63, rest = i >> 9;
            int ks = rest & 7; rest >>= 3;
            int mt = rest & 15; int l = rest >> 4;
            int mp = mt * 16 + (lane & 15);
            int orow = (mp >> 1) + (mp & 1) * 128;
            int k = ks * 32 + (lane >> 4) * 8 + j;
            int tap = k >> 7, c = k & 127;
            cw[i] = (_Float16)conv_w[(((size_t)l * 256 + orow) * 128 + c) * 2 + tap];
        } else if (i < ncw + nrs) {
            i -= ncw;
            int j = i & 7, lane = (i >> 3) & 63, rest = i >> 9;
            int ks = rest & 3; rest >>= 2;
            int mt = rest & 7; int l = rest >> 3;
            int m = mt * 16 + (lane & 15);
            int k = ks * 32 + (lane >> 4) * 8 + j;
            rsw[i] = (_Float16)res_w[((size_t)l * 128 + m) * 128 + k];
        } else if (i < ncw + nrs + nsk) {
            i -= ncw + nrs;
            int j = i & 7, lane = (i >> 3) & 63, rest = i >> 9;
            int ks = rest & 3; rest >>= 2;
            int mt = rest & 15; int l = rest >> 4;
            int m = mt * 16 + (lane & 15);
            int k = ks * 32 + (lane >> 4) * 8 + j;
            skw[i] = (_Float16)skip_w[((size_t)l * 256 + m) * 128 + k];
        } else if (i < ncw + nrs + nsk + nab) {
            i -= ncw + nrs + nsk;
            int j = i & 7, lane = (i >> 3) & 63, rest = i >> 9;
            int ks = rest & 7; int mt = rest >> 3;
            aw[i] = (_Float16)a_w[(mt * 16 + (lane & 15)) * 256 + ks * 32 + (lane >> 4) * 8 + j];
        } else if (i < ncw + nrs + nsk + 2 * nab) {
            i -= ncw + nrs + nsk + nab;
            int j = i & 7, lane = (i >> 3) & 63, rest = i >> 9;
            int ks = rest & 7; int mt = rest >> 3;
            bw[i] = (_Float16)b_w[(mt * 16 + (lane & 15)) * 256 + ks * 32 + (lane >> 4) * 8 + j];
        } else if (i < ncw + nrs + nsk + 2 * nab + ncb) {
            i -= ncw + nrs + nsk + 2 * nab;
            int mp = i & 255; int l = i >> 8;
            cbp[i] = conv_b[l * 256 + (mp >> 1) + (mp & 1) * 128];
        } else {
            i -= ncw + nrs + nsk + 2 * nab + ncb;
            float s = 0.f;
            for (int l = 0; l < NLAYERS; ++l) s += skip_b[l * 256 + i];
            ssum[i] = s;
        }
    }
}

// ---------------- front: h0 (f16, [n][t][c]) ----------------
__global__ void front_kernel(const float* __restrict__ x,
                             const float* __restrict__ w_shift,
                             const float* __restrict__ b_shift,
                             _Float16* __restrict__ h) {
    const int n = blockIdx.y;
    const int t = blockIdx.x * 256 + threadIdx.x;
    float x1 = (t >= 1) ? x[n * WLEN + t - 1] : 0.0f;
    float x2 = (t >= 2) ? x[n * WLEN + t - 2] : 0.0f;
    _Float16* hq = h + ((size_t)n * WLEN + t) * 128;
    #pragma unroll
    for (int c0 = 0; c0 < 128; c0 += 8) {
        half8 v;
        #pragma unroll
        for (int j = 0; j < 8; ++j) {
            int c = c0 + j;
            v[j] = (_Float16)fmaf(w_shift[2 * c], x2,
                                  fmaf(w_shift[2 * c + 1], x1, b_shift[c]));
        }
        *(half8*)&hq[c0] = v;
    }
}

// ---------------- fused stack kernel (templated window) ----------------
// Window rows w=0..WR-1 map to t = t0 - HALO + w. Layers d = 2^(E0+j),
// j=0..NL-1. Valid output rows of the last layer start before w = HALO;
// rows HALO..HALO+63 (= t0..t0+63) are exact. All NT row-tiles computed
// uniformly; tap0 row clamped to >=0 (clamped reads land in garbage rows
// never consumed by valid outputs). LDS pad-free + XOR swizzle (SX).
// amdgpu_waves_per_eu(2,4): cap occupancy target at 4 waves/EU -> firm
// 128-VGPR budget -> allocator must not spill to chase 8 waves/EU.
template <int E0, int NL, int NT, int HALO, bool FIRST>
__global__ __launch_bounds__(512)
__attribute__((amdgpu_waves_per_eu(2, 4))) void stack_kernel(
    const _Float16* __restrict__ h_in, _Float16* __restrict__ h_out,
    _Float16* __restrict__ chunk,
    const _Float16* __restrict__ cw0, const float* __restrict__ cb0,
    const _Float16* __restrict__ rsw0, const float* __restrict__ rb0,
    const _Float16* __restrict__ skw0, const float* __restrict__ ssum) {
    constexpr int WR = NT * 16;
    __shared__ _Float16 SMEM[2 * WR * 128];  // A: 40960 B; B: 57344 B
    _Float16* H = SMEM;             // h window, updated in place per layer
    _Float16* G = SMEM + WR * 128;  // gated
    const int n = blockIdx.y, tb = blockIdx.x, t0 = tb * TT;
    const int tid = threadIdx.x;
    const int wave = __builtin_amdgcn_readfirstlane(tid >> 6);  // 0..7
    const int lane = tid & 63, q = lane >> 4, ml = lane & 15;

    // ---- skip accumulator (persistent f32 across the NL layers)
    floatx4 sacc[2][4];
    if (FIRST) {
        #pragma unroll
        for (int mt = 0; mt < 2; ++mt)
            #pragma unroll
            for (int r = 0; r < 4; ++r) {
                float bias = ssum[32 * wave + mt * 16 + q * 4 + r];
                #pragma unroll
                for (int nt = 0; nt < 4; ++nt) sacc[mt][nt][r] = bias;
            }
    } else {
        const _Float16* cp = chunk + ((size_t)n * NTB + tb) * 16384;
        #pragma unroll
        for (int mt = 0; mt < 2; ++mt)
            #pragma unroll
            for (int nt = 0; nt < 4; ++nt) {
                size_t o = (size_t)((((wave * 2 + mt) * 4) + nt) * 64 + lane) * 4;
                half4 v = *(const half4*)&cp[o];
                #pragma unroll
                for (int r = 0; r < 4; ++r) sacc[mt][nt][r] = (float)v[r];
            }
    }

    // ---- stage WR-row window (t0-HALO .. t0+63); t<0 rows = 0 (causal pad)
    const _Float16* hn = h_in + (size_t)n * WLEN * 128;
    #pragma unroll
    for (int it = 0; it < (WR * 16 + 511) / 512; ++it) {
        int idx = it * 512 + tid;
        if (idx < WR * 16) {
            int seg = idx & 15;          // 16B segment (8 f16)
            int w = idx >> 4;            // window row
            int src_t = t0 - HALO + w;
            half8 v = (half8)(_Float16)0.0f;
            if (src_t >= 0)
                v = *(const half8*)&hn[(size_t)src_t * 128 + seg * 8];
            *(half8*)&H[SX(w, seg * 8)] = v;
        }
    }
    __syncthreads();

    const _Float16* cw  = cw0;
    const float*    cb  = cb0;
    const _Float16* rsw = rsw0;
    const float*    rb  = rb0;
    const _Float16* skw = skw0;

    #pragma clang loop unroll(disable)
    for (int j = 0; j < NL; ++j) {
        const int d = 1 << (E0 + j);

        // ---- conv GEMM + GLU over NT row-tiles in passes of <=4
        #pragma unroll
        for (int base = 0; base < NT; base += 4) {
            floatx4 acc[2][4];
            #pragma unroll
            for (int mt = 0; mt < 2; ++mt)
                #pragma unroll
                for (int r = 0; r < 4; ++r) {
                    float bias = cb[32 * wave + mt * 16 + q * 4 + r];
                    #pragma unroll
                    for (int nt = 0; nt < 4; ++nt) acc[mt][nt][r] = bias;
                }
            #pragma unroll
            for (int hp = 0; hp < 2; ++hp) {
                for (int ks = 0; ks < 4; ++ks) {
                    half8 a[2];
                    #pragma unroll
                    for (int mt = 0; mt < 2; ++mt)
                        a[mt] = *(const half8*)&cw[((((2 * wave + mt) * 8) + hp * 4 + ks) * 64 + lane) * 8];
                    #pragma unroll
                    for (int nt = 0; nt < 4; ++nt) {
                        if (base + nt < NT) {
                            int row = (base + nt) * 16 + ml;
                            if (!hp) { row -= d; if (row < 0) row = 0; }  // tap0 = t-d, clamped
                            half8 b = *(const half8*)&H[SX(row, ks * 32 + q * 8)];
                            #pragma unroll
                            for (int mt = 0; mt < 2; ++mt)
                                acc[mt][nt] = __builtin_amdgcn_mfma_f32_16x16x32_f16(a[mt], b, acc[mt][nt], 0, 0, 0);
                        }
                    }
                }
            }
            // GLU -> G (separate buffer from H: no barrier needed before write)
            #pragma unroll
            for (int mt = 0; mt < 2; ++mt)
                #pragma unroll
                for (int nt = 0; nt < 4; ++nt) {
                    if (base + nt < NT) {
                        float g0 = acc[mt][nt][0] * sigmoidf_(acc[mt][nt][1]);
                        float g1 = acc[mt][nt][2] * sigmoidf_(acc[mt][nt][3]);
                        _Float16 p[2] = {(_Float16)g0, (_Float16)g1};
                        *(uint32_t*)&G[SX((base + nt) * 16 + ml, 16 * wave + mt * 8 + 2 * q)] = *(uint32_t*)p;
                    }
                }
        }
        __syncthreads();  // G complete before skip/res read it

        // ---- skip GEMM over the valid tile (window rows HALO..HALO+63) -> sacc
        #pragma unroll
        for (int ks = 0; ks < 4; ++ks) {
            half8 a[2];
            #pragma unroll
            for (int mt = 0; mt < 2; ++mt)
                a[mt] = *(const half8*)&skw[((((2 * wave + mt) * 4) + ks) * 64 + lane) * 8];
            #pragma unroll
            for (int nt = 0; nt < 4; ++nt) {
                half8 b = *(const half8*)&G[SX(HALO + nt * 16 + ml, ks * 32 + q * 8)];
                #pragma unroll
                for (int mt = 0; mt < 2; ++mt)
                    sacc[mt][nt] = __builtin_amdgcn_mfma_f32_16x16x32_f16(a[mt], b, sacc[mt][nt], 0, 0, 0);
            }
        }

        // ---- res GEMM + in-place H update (wave owns 16-channel column block)
        #pragma unroll
        for (int base = 0; base < NT; base += 4) {
            floatx4 racc[4];
            #pragma unroll
            for (int r = 0; r < 4; ++r) {
                float bias = rb[16 * wave + q * 4 + r];
                #pragma unroll
                for (int nt = 0; nt < 4; ++nt) racc[nt][r] = bias;
            }
            #pragma unroll
            for (int ks = 0; ks < 4; ++ks) {
                half8 a = *(const half8*)&rsw[(((wave * 4) + ks) * 64 + lane) * 8];
                #pragma unroll
                for (int nt = 0; nt < 4; ++nt) {
                    if (base + nt < NT) {
                        half8 b = *(const half8*)&G[SX((base + nt) * 16 + ml, ks * 32 + q * 8)];
                        racc[nt] = __builtin_amdgcn_mfma_f32_16x16x32_f16(a, b, racc[nt], 0, 0, 0);
                    }
                }
            }
            #pragma unroll
            for (int nt = 0; nt < 4; ++nt) {
                if (base + nt < NT) {
                    int w = (base + nt) * 16 + ml;
                    int c = 16 * wave + q * 4;
                    half4 hv = *(const half4*)&H[SX(w, c)];
                    half4 o;
                    #pragma unroll
                    for (int r = 0; r < 4; ++r)
                        o[r] = (_Float16)(racc[nt][r] + (float)hv[r]);
                    *(half4*)&H[SX(w, c)] = o;
                }
            }
        }
        __syncthreads();  // H updated before next layer's conv reads

        cw  += 65536; cb += 256; rsw += 16384; rb += 128; skw += 32768;
    }

    // ---- store h_out: window rows HALO..HALO+63 -> t0..t0+63
    _Float16* ho = h_out + (size_t)n * WLEN * 128;
    #pragma unroll
    for (int it = 0; it < 2; ++it) {
        int idx = it * 512 + tid;        // 0..1023
        int seg = idx & 15;
        int w64 = idx >> 4;              // 0..63
        *(half8*)&ho[(size_t)(t0 + w64) * 128 + seg * 8] =
            *(const half8*)&H[SX(HALO + w64, seg * 8)];
    }

    // ---- store skip accumulator (f16 frag-linear, same layout as singles/head)
    {
        _Float16* cp = chunk + ((size_t)n * NTB + tb) * 16384;
        #pragma unroll
        for (int mt = 0; mt < 2; ++mt)
            #pragma unroll
            for (int nt = 0; nt < 4; ++nt) {
                size_t o = (size_t)((((wave * 2 + mt) * 4) + nt) * 64 + lane) * 4;
                half4 v;
                #pragma unroll
                for (int r = 0; r < 4; ++r) v[r] = (_Float16)sacc[mt][nt][r];
                *(half4*)&cp[o] = v;
            }
    }
}

// ---------------- single residual layer (d>=64), 8 waves (round-7) ----------------
__global__ __launch_bounds__(512, 8) void layer_kernel(
    const _Float16* __restrict__ h_in, _Float16* __restrict__ h_out,
    _Float16* __restrict__ chunk,
    const _Float16* __restrict__ cw, const float* __restrict__ cb,
    const _Float16* __restrict__ rsw, const float* __restrict__ rb,
    const _Float16* __restrict__ skw, int d) {
    __shared__ _Float16 SMEM[2 * TT * GROW];  // 34816 B -> 4 blocks/CU
    _Float16* X0 = SMEM;
    _Float16* X1 = SMEM + TT * GROW;
    _Float16* G  = X0;  // alias: tap0 dead after conv reads
    const int n = blockIdx.y, tb = blockIdx.x, t0 = tb * TT;
    const int tid = threadIdx.x;
    const int wave = __builtin_amdgcn_readfirstlane(tid >> 6);  // 0..7
    const int lane = tid & 63, q = lane >> 4, ml = lane & 15;

    const _Float16* hn = h_in + (size_t)n * WLEN * 128;
    #pragma unroll
    for (int it = 0; it < 4; ++it) {
        int idx = it * 512 + tid;
        int seg = idx & 15;
        int rowc = (idx >> 4) & 63;
        int tap = idx >> 10;
        int src_t = t0 + rowc - (tap ? 0 : d);
        half8 v = (half8)(_Float16)0.0f;
        if (src_t >= 0)
            v = *(const half8*)&hn[(size_t)src_t * 128 + seg * 8];
        _Float16* Xb = tap ? X1 : X0;
        *(half8*)&Xb[rowc * GROW + seg * 8] = v;
    }
    __syncthreads();

    floatx4 acc[2][4];
    #pragma unroll
    for (int mt = 0; mt < 2; ++mt)
        #pragma unroll
        for (int r = 0; r < 4; ++r) {
            float bias = cb[32 * wave + mt * 16 + q * 4 + r];
            #pragma unroll
            for (int nt = 0; nt < 4; ++nt) acc[mt][nt][r] = bias;
        }
    #pragma unroll
    for (int hp = 0; hp < 2; ++hp) {
        const _Float16* Xb = hp ? X1 : X0;
        for (int ks = 0; ks < 4; ++ks) {
            half8 a[2];
            #pragma unroll
            for (int mt = 0; mt < 2; ++mt)
                a[mt] = *(const half8*)&cw[((((2 * wave + mt) * 8) + hp * 4 + ks) * 64 + lane) * 8];
            #pragma unroll
            for (int nt = 0; nt < 4; ++nt) {
                half8 b = *(const half8*)&Xb[(nt * 16 + ml) * GROW + ks * 32 + q * 8];
                #pragma unroll
                for (int mt = 0; mt < 2; ++mt)
                    acc[mt][nt] = __builtin_amdgcn_mfma_f32_16x16x32_f16(a[mt], b, acc[mt][nt], 0, 0, 0);
            }
        }
    }
    __syncthreads();

    #pragma unroll
    for (int mt = 0; mt < 2; ++mt)
        #pragma unroll
        for (int nt = 0; nt < 4; ++nt) {
            float g0 = acc[mt][nt][0] * sigmoidf_(acc[mt][nt][1]);
            float g1 = acc[mt][nt][2] * sigmoidf_(acc[mt][nt][3]);
            _Float16 p[2] = {(_Float16)g0, (_Float16)g1};
            *(uint32_t*)&G[(nt * 16 + ml) * GROW + 16 * wave + mt * 8 + 2 * q] = *(uint32_t*)p;
        }
    __syncthreads();

    {
        floatx4 sacc[2][4];
        #pragma unroll
        for (int mt = 0; mt < 2; ++mt)
            #pragma unroll
            for (int nt = 0; nt < 4; ++nt)
                #pragma unroll
                for (int r = 0; r < 4; ++r) sacc[mt][nt][r] = 0.0f;
        #pragma unroll
        for (int ks = 0; ks < 4; ++ks) {
            half8 a[2];
            #pragma unroll
            for (int mt = 0; mt < 2; ++mt)
                a[mt] = *(const half8*)&skw[((((2 * wave + mt) * 4) + ks) * 64 + lane) * 8];
            #pragma unroll
            for (int nt = 0; nt < 4; ++nt) {
                half8 b = *(const half8*)&G[(nt * 16 + ml) * GROW + ks * 32 + q * 8];
                #pragma unroll
                for (int mt = 0; mt < 2; ++mt)
                    sacc[mt][nt] = __builtin_amdgcn_mfma_f32_16x16x32_f16(a[mt], b, sacc[mt][nt], 0, 0, 0);
            }
        }
        _Float16* cp = chunk + ((size_t)n * NTB + tb) * 16384;
        #pragma unroll
        for (int mt = 0; mt < 2; ++mt)
            #pragma unroll
            for (int nt = 0; nt < 4; ++nt) {
                size_t o = (size_t)((((wave * 2 + mt) * 4) + nt) * 64 + lane) * 4;
                half4 v = *(const half4*)&cp[o];
                half4 w;
                #pragma unroll
                for (int r = 0; r < 4; ++r)
                    w[r] = (_Float16)(sacc[mt][nt][r] + (float)v[r]);
                *(half4*)&cp[o] = w;
            }
    }

    {
        floatx4 racc[4];
        #pragma unroll
        for (int r = 0; r < 4; ++r) {
            float bias = rb[16 * wave + q * 4 + r];
            #pragma unroll
            for (int nt = 0; nt < 4; ++nt) racc[nt][r] = bias;
        }
        #pragma unroll
        for (int ks = 0; ks < 4; ++ks) {
            half8 a = *(const half8*)&rsw[(((wave * 4) + ks) * 64 + lane) * 8];
            #pragma unroll
            for (int nt = 0; nt < 4; ++nt) {
                half8 b = *(const half8*)&G[(nt * 16 + ml) * GROW + ks * 32 + q * 8];
                racc[nt] = __builtin_amdgcn_mfma_f32_16x16x32_f16(a, b, racc[nt], 0, 0, 0);
            }
        }
        _Float16* ho = h_out + (size_t)n * WLEN * 128;
        #pragma unroll
        for (int nt = 0; nt < 4; ++nt) {
            int tt = nt * 16 + ml;
            int c = 16 * wave + q * 4;
            half4 hv = *(const half4*)&X1[tt * GROW + c];
            half4 o;
            #pragma unroll
            for (int r = 0; r < 4; ++r)
                o[r] = (_Float16)(racc[nt][r] + (float)hv[r]);
            *(half4*)&ho[(size_t)(t0 + tt) * 128 + c] = o;
        }
    }
}

// ---------------- head (round-7, 8 waves) ----------------
__global__ __launch_bounds__(512, 8) void head_kernel(
    float* __restrict__ out, const _Float16* __restrict__ chunk,
    const _Float16* __restrict__ aw, const float* __restrict__ ab,
    const _Float16* __restrict__ bw, const float* __restrict__ bb) {
    __shared__ _Float16 X[TT * XROW];
    const int n = blockIdx.y, tb = blockIdx.x, t0 = tb * TT;
    const int tid = threadIdx.x;
    const int wave = __builtin_amdgcn_readfirstlane(tid >> 6);
    const int lane = tid & 63, q = lane >> 4, ml = lane & 15;

    {
        const _Float16* cp = chunk + ((size_t)n * NTB + tb) * 16384;
        #pragma unroll
        for (int mt = 0; mt < 2; ++mt)
            #pragma unroll
            for (int nt = 0; nt < 4; ++nt) {
                size_t o = (size_t)((((wave * 2 + mt) * 4) + nt) * 64 + lane) * 4;
                half4 v = *(const half4*)&cp[o];
                half4 z;
                #pragma unroll
                for (int r = 0; r < 4; ++r)
                    z[r] = (_Float16)fmaxf((float)v[r], 0.0f);
                *(half4*)&X[(nt * 16 + ml) * XROW + 32 * wave + mt * 16 + q * 4] = z;
            }
    }
    __syncthreads();

    floatx4 acc[2][4];
    #pragma unroll
    for (int mt = 0; mt < 2; ++mt)
        #pragma unroll
        for (int r = 0; r < 4; ++r) {
            float bias = ab[32 * wave + mt * 16 + q * 4 + r];
            #pragma unroll
            for (int nt = 0; nt < 4; ++nt) acc[mt][nt][r] = bias;
        }
    for (int ks = 0; ks < 8; ++ks) {
        half8 a[2];
        #pragma unroll
        for (int mt = 0; mt < 2; ++mt)
            a[mt] = *(const half8*)&aw[((((2 * wave + mt) * 8) + ks) * 64 + lane) * 8];
        #pragma unroll
        for (int nt = 0; nt < 4; ++nt) {
            half8 b = *(const half8*)&X[(nt * 16 + ml) * XROW + ks * 32 + q * 8];
            #pragma unroll
            for (int mt = 0; mt < 2; ++mt)
                acc[mt][nt] = __builtin_amdgcn_mfma_f32_16x16x32_f16(a[mt], b, acc[mt][nt], 0, 0, 0);
        }
    }
    __syncthreads();
    #pragma unroll
    for (int mt = 0; mt < 2; ++mt)
        #pragma unroll
        for (int nt = 0; nt < 4; ++nt) {
            half4 z;
            #pragma unroll
            for (int r = 0; r < 4; ++r)
                z[r] = (_Float16)fmaxf(acc[mt][nt][r], 0.0f);
            *(half4*)&X[(nt * 16 + ml) * XROW + 32 * wave + mt * 16 + q * 4] = z;
        }
    __syncthreads();

    #pragma unroll
    for (int mt = 0; mt < 2; ++mt)
        #pragma unroll
        for (int r = 0; r < 4; ++r) {
            float bias = bb[32 * wave + mt * 16 + q * 4 + r];
            #pragma unroll
            for (int nt = 0; nt < 4; ++nt) acc[mt][nt][r] = bias;
        }
    for (int ks = 0; ks < 8; ++ks) {
        half8 a[2];
        #pragma unroll
        for (int mt = 0; mt < 2; ++mt)
            a[mt] = *(const half8*)&bw[((((2 * wave + mt) * 8) + ks) * 64 + lane) * 8];
        #pragma unroll
        for (int nt = 0; nt < 4; ++nt) {
            half8 b = *(const half8*)&X[(nt * 16 + ml) * XROW + ks * 32 + q * 8];
            #pragma unroll
            for (int mt = 0; mt < 2; ++mt)
                acc[mt][nt] = __builtin_amdgcn_mfma_f32_16x16x32_f16(a[mt], b, acc[mt][nt], 0, 0, 0);
        }
    }
    float* on = out + (size_t)n * S * WLEN;
    #pragma unroll
    for (int mt = 0; mt < 2; ++mt)
        #pragma unroll
        for (int nt = 0; nt < 4; ++nt)
            #pragma unroll
            for (int r = 0; r < 4; ++r) {
                int o = 32 * wave + mt * 16 + q * 4 + r;
                int tt = t0 + nt * 16 + ml;
                on[(size_t)o * WLEN + tt] = acc[mt][nt][r];
            }
}

extern "C" void kernel_launch(void* const* d_in, const int* in_sizes, int n_in,
                              void* d_out, int out_size, void* d_ws, size_t ws_size,
                              hipStream_t stream) {
    (void)in_sizes; (void)n_in; (void)out_size; (void)ws_size;
    const float* x       = (const float*)d_in[0];
    const float* w_shift = (const float*)d_in[1];
    const float* b_shift = (const float*)d_in[2];
    const float* conv_w  = (const float*)d_in[3];
    const float* conv_b  = (const float*)d_in[4];
    const float* res_w   = (const float*)d_in[5];
    const float* res_b   = (const float*)d_in[6];
    const float* skip_w  = (const float*)d_in[7];
    const float* skip_b  = (const float*)d_in[8];
    const float* a_w     = (const float*)d_in[9];
    const float* a_b     = (const float*)d_in[10];
    const float* b_w     = (const float*)d_in[11];
    const float* b_b     = (const float*)d_in[12];
    float* out = (float*)d_out;

    char* ws = (char*)d_ws;
    size_t off = 0;
    _Float16* hA    = (_Float16*)(ws + off); off += (size_t)NB * WLEN * 128 * 2;
    _Float16* hB    = (_Float16*)(ws + off); off += (size_t)NB * WLEN * 128 * 2;
    _Float16* chunk = (_Float16*)(ws + off); off += (size_t)NB * NTB * 16384 * 2;
    _Float16* cw  = (_Float16*)(ws + off); off += (size_t)NLAYERS * 256 * 256 * 2;
    _Float16* rsw = (_Float16*)(ws + off); off += (size_t)NLAYERS * 128 * 128 * 2;
    _Float16* skw = (_Float16*)(ws + off); off += (size_t)NLAYERS * 256 * 128 * 2;
    _Float16* aw  = (_Float16*)(ws + off); off += 256 * 256 * 2;
    _Float16* bw  = (_Float16*)(ws + off); off += 256 * 256 * 2;
    float* cbp  = (float*)(ws + off); off += (size_t)NLAYERS * 256 * 4;
    float* ssum = (float*)(ws + off); off += 256 * 4;
    // total ~74.3 MB

    prep_kernel<<<512, 256, 0, stream>>>(conv_w, res_w, skip_w, a_w, b_w,
                                         conv_b, skip_b,
                                         cw, rsw, skw, aw, bw, cbp, ssum);
    front_kernel<<<dim3(WLEN / 256, NB), 256, 0, stream>>>(x, w_shift, b_shift, hA);

    const dim3 grid(NTB, NB);
    _Float16* hin = hA;
    _Float16* hout = hB;
    for (int s = 0; s < 3; ++s) {
        const int l0 = s * 10;
        // stackA: layers l0..l0+3 (d=1,2,4,8), 80-row window
        if (s == 0)
            stack_kernel<0, 4, 5, 16, true><<<grid, 512, 0, stream>>>(
                hin, hout, chunk,
                cw + (size_t)l0 * 65536, cbp + l0 * 256,
                rsw + (size_t)l0 * 16384, res_b + l0 * 128,
                skw + (size_t)l0 * 32768, ssum);
        else
            stack_kernel<0, 4, 5, 16, false><<<grid, 512, 0, stream>>>(
                hin, hout, chunk,
                cw + (size_t)l0 * 65536, cbp + l0 * 256,
                rsw + (size_t)l0 * 16384, res_b + l0 * 128,
                skw + (size_t)l0 * 32768, ssum);
        { _Float16* tmp = hin; hin = hout; hout = tmp; }
        // stackB: layers l0+4, l0+5 (d=16,32), 112-row window
        {
            const int lb = l0 + 4;
            stack_kernel<4, 2, 7, 48, false><<<grid, 512, 0, stream>>>(
                hin, hout, chunk,
                cw + (size_t)lb * 65536, cbp + lb * 256,
                rsw + (size_t)lb * 16384, res_b + lb * 128,
                skw + (size_t)lb * 32768, ssum);
            _Float16* tmp = hin; hin = hout; hout = tmp;
        }
        // single layers l0+6 .. l0+9 (d = 64..512)
        for (int jj = 6; jj < 10; ++jj) {
            const int l = l0 + jj;
            const int dil = 1 << jj;
            layer_kernel<<<grid, 512, 0, stream>>>(
                hin, hout, chunk,
                cw + (size_t)l * 65536, cbp + l * 256,
                rsw + (size_t)l * 16384, res_b + l * 128,
                skw + (size_t)l * 32768, dil);
            _Float16* tmp = hin; hin = hout; hout = tmp;
        }
    }

    head_kernel<<<grid, 512, 0, stream>>>(out, chunk, aw, a_b, bw, b_b);
}

// Round 14
// 1053.847 us; speedup vs baseline: 2.5589x; 1.0576x over previous
//
#include <hip/hip_runtime.h>
#include <math.h>

// WaveNet forward, round 12: keep stackA, drop stackB.
// - Round-11 postmortem: spill fix confirmed (stackA VGPR 112, FETCH 35.7MB,
//   WRITE 49MB, no scratch). But durations: stackA 129 us vs 136 us of the 4
//   singles it replaces (marginal win); stackB ~88 us vs 68 us of 2 singles
//   (a LOSS - 75% halo recompute is compute-negative). Fusion only pays when
//   recompute <= 25%.
// - Change (one variable): d=16,32 go back to the verified single-layer
//   kernel; stackA (d=1,2,4,8, 80-row window, 25% recompute) stays with
//   amdgpu_waves_per_eu(2,4). Expected net -66 us.
// - Coop/grid.sync stays deleted (5x regression, round 4).
//
// MFMA 16x16x32_f16: A lane: A[m=lane&15][k=(lane>>4)*8+j]; D lane:
// D[row=(lane>>4)*4+reg][col=lane&15]. Conv A-rows interleaved (a0,b0,a1,b1..)
// so GLU happens in registers. Conv K order: k = tap*128 + c.

#define NB 4
#define WLEN 16384
#define C 128
#define S 256
#define NLAYERS 30
#define TT 64
#define NTB (WLEN / TT)   // 256 tiles per sample
#define XROW 264          // head X row stride (f16): 256 + 8 pad
#define GROW 136          // single-layer tile row stride (f16): 128 + 8 pad

// swizzled f16 index into a pad-free 128-col row (stack kernel only)
#define SX(row, c) ((row) * 128 + ((c) ^ (((row) & 7) << 3)))

typedef _Float16 half8 __attribute__((ext_vector_type(8)));
typedef _Float16 half4 __attribute__((ext_vector_type(4)));
typedef float floatx4 __attribute__((ext_vector_type(4)));

__device__ __forceinline__ float sigmoidf_(float v) {
    return 1.0f / (1.0f + __expf(-v));
}

// ---------------- weight packing (unchanged layouts) ----------------
__global__ void prep_kernel(const float* __restrict__ conv_w,
                            const float* __restrict__ res_w,
                            const float* __restrict__ skip_w,
                            const float* __restrict__ a_w,
                            const float* __restrict__ b_w,
                            const float* __restrict__ conv_b,
                            const float* __restrict__ skip_b,
                            _Float16* __restrict__ cw,
                            _Float16* __restrict__ rsw,
                            _Float16* __restrict__ skw,
                            _Float16* __restrict__ aw,
                            _Float16* __restrict__ bw,
                            float* __restrict__ cbp,
                            float* __restrict__ ssum) {
    const int ncw = NLAYERS * 256 * 256;
    const int nrs = NLAYERS * 128 * 128;
    const int nsk = NLAYERS * 256 * 128;
    const int nab = 256 * 256;
    const int ncb = NLAYERS * 256;
    const int total = ncw + nrs + nsk + nab + nab + ncb + 256;
    for (int idx = blockIdx.x * blockDim.x + threadIdx.x; idx < total;
         idx += gridDim.x * blockDim.x) {
        int i = idx;
        if (i < ncw) {
            int j = i & 7, lane = (i >> 3) & 63, rest = i >> 9;
            int ks = rest & 7; rest >>= 3;
            int mt = rest & 15; int l = rest >> 4;
            int mp = mt * 16 + (lane & 15);
            int orow = (mp >> 1) + (mp & 1) * 128;
            int k = ks * 32 + (lane >> 4) * 8 + j;
            int tap = k >> 7, c = k & 127;
            cw[i] = (_Float16)conv_w[(((size_t)l * 256 + orow) * 128 + c) * 2 + tap];
        } else if (i < ncw + nrs) {
            i -= ncw;
            int j = i & 7, lane = (i >> 3) & 63, rest = i >> 9;
            int ks = rest & 3; rest >>= 2;
            int mt = rest & 7; int l = rest >> 3;
            int m = mt * 16 + (lane & 15);
            int k = ks * 32 + (lane >> 4) * 8 + j;
            rsw[i] = (_Float16)res_w[((size_t)l * 128 + m) * 128 + k];
        } else if (i < ncw + nrs + nsk) {
            i -= ncw + nrs;
            int j = i & 7, lane = (i >> 3) & 63, rest = i >> 9;
            int ks = rest & 3; rest >>= 2;
            int mt = rest & 15; int l = rest >> 4;
            int m = mt * 16 + (lane & 15);
            int k = ks * 32 + (lane >> 4) * 8 + j;
            skw[i] = (_Float16)skip_w[((size_t)l * 256 + m) * 128 + k];
        } else if (i < ncw + nrs + nsk + nab) {
            i -= ncw + nrs + nsk;
            int j = i & 7, lane = (i >> 3) & 63, rest = i >> 9;
            int ks = rest & 7; int mt = rest >> 3;
            aw[i] = (_Float16)a_w[(mt * 16 + (lane & 15)) * 256 + ks * 32 + (lane >> 4) * 8 + j];
        } else if (i < ncw + nrs + nsk + 2 * nab) {
            i -= ncw + nrs + nsk + nab;
            int j = i & 7, lane = (i >> 3) & 63, rest = i >> 9;
            int ks = rest & 7; int mt = rest >> 3;
            bw[i] = (_Float16)b_w[(mt * 16 + (lane & 15)) * 256 + ks * 32 + (lane >> 4) * 8 + j];
        } else if (i < ncw + nrs + nsk + 2 * nab + ncb) {
            i -= ncw + nrs + nsk + 2 * nab;
            int mp = i & 255; int l = i >> 8;
            cbp[i] = conv_b[l * 256 + (mp >> 1) + (mp & 1) * 128];
        } else {
            i -= ncw + nrs + nsk + 2 * nab + ncb;
            float s = 0.f;
            for (int l = 0; l < NLAYERS; ++l) s += skip_b[l * 256 + i];
            ssum[i] = s;
        }
    }
}

// ---------------- front: h0 (f16, [n][t][c]) ----------------
__global__ void front_kernel(const float* __restrict__ x,
                             const float* __restrict__ w_shift,
                             const float* __restrict__ b_shift,
                             _Float16* __restrict__ h) {
    const int n = blockIdx.y;
    const int t = blockIdx.x * 256 + threadIdx.x;
    float x1 = (t >= 1) ? x[n * WLEN + t - 1] : 0.0f;
    float x2 = (t >= 2) ? x[n * WLEN + t - 2] : 0.0f;
    _Float16* hq = h + ((size_t)n * WLEN + t) * 128;
    #pragma unroll
    for (int c0 = 0; c0 < 128; c0 += 8) {
        half8 v;
        #pragma unroll
        for (int j = 0; j < 8; ++j) {
            int c = c0 + j;
            v[j] = (_Float16)fmaf(w_shift[2 * c], x2,
                                  fmaf(w_shift[2 * c + 1], x1, b_shift[c]));
        }
        *(half8*)&hq[c0] = v;
    }
}

// ---------------- fused stack kernel (d=1,2,4,8 only) ----------------
// Window rows w=0..79 map to t = t0-16+w. Valid rows 16..79 = t0..t0+63.
// All 5 row-tiles computed uniformly; tap0 row clamped to >=0. LDS pad-free
// + XOR swizzle (SX). amdgpu_waves_per_eu(2,4): firm 128-VGPR budget, no
// spill (round-11 verified: VGPR 112, FETCH 35.7MB, WRITE 49MB).
template <int E0, int NL, int NT, int HALO, bool FIRST>
__global__ __launch_bounds__(512)
__attribute__((amdgpu_waves_per_eu(2, 4))) void stack_kernel(
    const _Float16* __restrict__ h_in, _Float16* __restrict__ h_out,
    _Float16* __restrict__ chunk,
    const _Float16* __restrict__ cw0, const float* __restrict__ cb0,
    const _Float16* __restrict__ rsw0, const float* __restrict__ rb0,
    const _Float16* __restrict__ skw0, const float* __restrict__ ssum) {
    constexpr int WR = NT * 16;
    __shared__ _Float16 SMEM[2 * WR * 128];  // 40960 B
    _Float16* H = SMEM;             // h window, updated in place per layer
    _Float16* G = SMEM + WR * 128;  // gated
    const int n = blockIdx.y, tb = blockIdx.x, t0 = tb * TT;
    const int tid = threadIdx.x;
    const int wave = __builtin_amdgcn_readfirstlane(tid >> 6);  // 0..7
    const int lane = tid & 63, q = lane >> 4, ml = lane & 15;

    // ---- skip accumulator (persistent f32 across the NL layers)
    floatx4 sacc[2][4];
    if (FIRST) {
        #pragma unroll
        for (int mt = 0; mt < 2; ++mt)
            #pragma unroll
            for (int r = 0; r < 4; ++r) {
                float bias = ssum[32 * wave + mt * 16 + q * 4 + r];
                #pragma unroll
                for (int nt = 0; nt < 4; ++nt) sacc[mt][nt][r] = bias;
            }
    } else {
        const _Float16* cp = chunk + ((size_t)n * NTB + tb) * 16384;
        #pragma unroll
        for (int mt = 0; mt < 2; ++mt)
            #pragma unroll
            for (int nt = 0; nt < 4; ++nt) {
                size_t o = (size_t)((((wave * 2 + mt) * 4) + nt) * 64 + lane) * 4;
                half4 v = *(const half4*)&cp[o];
                #pragma unroll
                for (int r = 0; r < 4; ++r) sacc[mt][nt][r] = (float)v[r];
            }
    }

    // ---- stage WR-row window (t0-HALO .. t0+63); t<0 rows = 0 (causal pad)
    const _Float16* hn = h_in + (size_t)n * WLEN * 128;
    #pragma unroll
    for (int it = 0; it < (WR * 16 + 511) / 512; ++it) {
        int idx = it * 512 + tid;
        if (idx < WR * 16) {
            int seg = idx & 15;          // 16B segment (8 f16)
            int w = idx >> 4;            // window row
            int src_t = t0 - HALO + w;
            half8 v = (half8)(_Float16)0.0f;
            if (src_t >= 0)
                v = *(const half8*)&hn[(size_t)src_t * 128 + seg * 8];
            *(half8*)&H[SX(w, seg * 8)] = v;
        }
    }
    __syncthreads();

    const _Float16* cw  = cw0;
    const float*    cb  = cb0;
    const _Float16* rsw = rsw0;
    const float*    rb  = rb0;
    const _Float16* skw = skw0;

    #pragma clang loop unroll(disable)
    for (int j = 0; j < NL; ++j) {
        const int d = 1 << (E0 + j);

        // ---- conv GEMM + GLU over NT row-tiles in passes of <=4
        #pragma unroll
        for (int base = 0; base < NT; base += 4) {
            floatx4 acc[2][4];
            #pragma unroll
            for (int mt = 0; mt < 2; ++mt)
                #pragma unroll
                for (int r = 0; r < 4; ++r) {
                    float bias = cb[32 * wave + mt * 16 + q * 4 + r];
                    #pragma unroll
                    for (int nt = 0; nt < 4; ++nt) acc[mt][nt][r] = bias;
                }
            #pragma unroll
            for (int hp = 0; hp < 2; ++hp) {
                for (int ks = 0; ks < 4; ++ks) {
                    half8 a[2];
                    #pragma unroll
                    for (int mt = 0; mt < 2; ++mt)
                        a[mt] = *(const half8*)&cw[((((2 * wave + mt) * 8) + hp * 4 + ks) * 64 + lane) * 8];
                    #pragma unroll
                    for (int nt = 0; nt < 4; ++nt) {
                        if (base + nt < NT) {
                            int row = (base + nt) * 16 + ml;
                            if (!hp) { row -= d; if (row < 0) row = 0; }  // tap0 = t-d, clamped
                            half8 b = *(const half8*)&H[SX(row, ks * 32 + q * 8)];
                            #pragma unroll
                            for (int mt = 0; mt < 2; ++mt)
                                acc[mt][nt] = __builtin_amdgcn_mfma_f32_16x16x32_f16(a[mt], b, acc[mt][nt], 0, 0, 0);
                        }
                    }
                }
            }
            // GLU -> G (separate buffer from H: no barrier needed before write)
            #pragma unroll
            for (int mt = 0; mt < 2; ++mt)
                #pragma unroll
                for (int nt = 0; nt < 4; ++nt) {
                    if (base + nt < NT) {
                        float g0 = acc[mt][nt][0] * sigmoidf_(acc[mt][nt][1]);
                        float g1 = acc[mt][nt][2] * sigmoidf_(acc[mt][nt][3]);
                        _Float16 p[2] = {(_Float16)g0, (_Float16)g1};
                        *(uint32_t*)&G[SX((base + nt) * 16 + ml, 16 * wave + mt * 8 + 2 * q)] = *(uint32_t*)p;
                    }
                }
        }
        __syncthreads();  // G complete before skip/res read it

        // ---- skip GEMM over the valid tile (window rows HALO..HALO+63) -> sacc
        #pragma unroll
        for (int ks = 0; ks < 4; ++ks) {
            half8 a[2];
            #pragma unroll
            for (int mt = 0; mt < 2; ++mt)
                a[mt] = *(const half8*)&skw[((((2 * wave + mt) * 4) + ks) * 64 + lane) * 8];
            #pragma unroll
            for (int nt = 0; nt < 4; ++nt) {
                half8 b = *(const half8*)&G[SX(HALO + nt * 16 + ml, ks * 32 + q * 8)];
                #pragma unroll
                for (int mt = 0; mt < 2; ++mt)
                    sacc[mt][nt] = __builtin_amdgcn_mfma_f32_16x16x32_f16(a[mt], b, sacc[mt][nt], 0, 0, 0);
            }
        }

        // ---- res GEMM + in-place H update (wave owns 16-channel column block)
        #pragma unroll
        for (int base = 0; base < NT; base += 4) {
            floatx4 racc[4];
            #pragma unroll
            for (int r = 0; r < 4; ++r) {
                float bias = rb[16 * wave + q * 4 + r];
                #pragma unroll
                for (int nt = 0; nt < 4; ++nt) racc[nt][r] = bias;
            }
            #pragma unroll
            for (int ks = 0; ks < 4; ++ks) {
                half8 a = *(const half8*)&rsw[(((wave * 4) + ks) * 64 + lane) * 8];
                #pragma unroll
                for (int nt = 0; nt < 4; ++nt) {
                    if (base + nt < NT) {
                        half8 b = *(const half8*)&G[SX((base + nt) * 16 + ml, ks * 32 + q * 8)];
                        racc[nt] = __builtin_amdgcn_mfma_f32_16x16x32_f16(a, b, racc[nt], 0, 0, 0);
                    }
                }
            }
            #pragma unroll
            for (int nt = 0; nt < 4; ++nt) {
                if (base + nt < NT) {
                    int w = (base + nt) * 16 + ml;
                    int c = 16 * wave + q * 4;
                    half4 hv = *(const half4*)&H[SX(w, c)];
                    half4 o;
                    #pragma unroll
                    for (int r = 0; r < 4; ++r)
                        o[r] = (_Float16)(racc[nt][r] + (float)hv[r]);
                    *(half4*)&H[SX(w, c)] = o;
                }
            }
        }
        __syncthreads();  // H updated before next layer's conv reads

        cw  += 65536; cb += 256; rsw += 16384; rb += 128; skw += 32768;
    }

    // ---- store h_out: window rows HALO..HALO+63 -> t0..t0+63
    _Float16* ho = h_out + (size_t)n * WLEN * 128;
    #pragma unroll
    for (int it = 0; it < 2; ++it) {
        int idx = it * 512 + tid;        // 0..1023
        int seg = idx & 15;
        int w64 = idx >> 4;              // 0..63
        *(half8*)&ho[(size_t)(t0 + w64) * 128 + seg * 8] =
            *(const half8*)&H[SX(HALO + w64, seg * 8)];
    }

    // ---- store skip accumulator (f16 frag-linear, same layout as singles/head)
    {
        _Float16* cp = chunk + ((size_t)n * NTB + tb) * 16384;
        #pragma unroll
        for (int mt = 0; mt < 2; ++mt)
            #pragma unroll
            for (int nt = 0; nt < 4; ++nt) {
                size_t o = (size_t)((((wave * 2 + mt) * 4) + nt) * 64 + lane) * 4;
                half4 v;
                #pragma unroll
                for (int r = 0; r < 4; ++r) v[r] = (_Float16)sacc[mt][nt][r];
                *(half4*)&cp[o] = v;
            }
    }
}

// ---------------- single residual layer (d>=16), 8 waves (round-7) ----------------
__global__ __launch_bounds__(512, 8) void layer_kernel(
    const _Float16* __restrict__ h_in, _Float16* __restrict__ h_out,
    _Float16* __restrict__ chunk,
    const _Float16* __restrict__ cw, const float* __restrict__ cb,
    const _Float16* __restrict__ rsw, const float* __restrict__ rb,
    const _Float16* __restrict__ skw, int d) {
    __shared__ _Float16 SMEM[2 * TT * GROW];  // 34816 B -> 4 blocks/CU
    _Float16* X0 = SMEM;
    _Float16* X1 = SMEM + TT * GROW;
    _Float16* G  = X0;  // alias: tap0 dead after conv reads
    const int n = blockIdx.y, tb = blockIdx.x, t0 = tb * TT;
    const int tid = threadIdx.x;
    const int wave = __builtin_amdgcn_readfirstlane(tid >> 6);  // 0..7
    const int lane = tid & 63, q = lane >> 4, ml = lane & 15;

    const _Float16* hn = h_in + (size_t)n * WLEN * 128;
    #pragma unroll
    for (int it = 0; it < 4; ++it) {
        int idx = it * 512 + tid;
        int seg = idx & 15;
        int rowc = (idx >> 4) & 63;
        int tap = idx >> 10;
        int src_t = t0 + rowc - (tap ? 0 : d);
        half8 v = (half8)(_Float16)0.0f;
        if (src_t >= 0)
            v = *(const half8*)&hn[(size_t)src_t * 128 + seg * 8];
        _Float16* Xb = tap ? X1 : X0;
        *(half8*)&Xb[rowc * GROW + seg * 8] = v;
    }
    __syncthreads();

    floatx4 acc[2][4];
    #pragma unroll
    for (int mt = 0; mt < 2; ++mt)
        #pragma unroll
        for (int r = 0; r < 4; ++r) {
            float bias = cb[32 * wave + mt * 16 + q * 4 + r];
            #pragma unroll
            for (int nt = 0; nt < 4; ++nt) acc[mt][nt][r] = bias;
        }
    #pragma unroll
    for (int hp = 0; hp < 2; ++hp) {
        const _Float16* Xb = hp ? X1 : X0;
        for (int ks = 0; ks < 4; ++ks) {
            half8 a[2];
            #pragma unroll
            for (int mt = 0; mt < 2; ++mt)
                a[mt] = *(const half8*)&cw[((((2 * wave + mt) * 8) + hp * 4 + ks) * 64 + lane) * 8];
            #pragma unroll
            for (int nt = 0; nt < 4; ++nt) {
                half8 b = *(const half8*)&Xb[(nt * 16 + ml) * GROW + ks * 32 + q * 8];
                #pragma unroll
                for (int mt = 0; mt < 2; ++mt)
                    acc[mt][nt] = __builtin_amdgcn_mfma_f32_16x16x32_f16(a[mt], b, acc[mt][nt], 0, 0, 0);
            }
        }
    }
    __syncthreads();

    #pragma unroll
    for (int mt = 0; mt < 2; ++mt)
        #pragma unroll
        for (int nt = 0; nt < 4; ++nt) {
            float g0 = acc[mt][nt][0] * sigmoidf_(acc[mt][nt][1]);
            float g1 = acc[mt][nt][2] * sigmoidf_(acc[mt][nt][3]);
            _Float16 p[2] = {(_Float16)g0, (_Float16)g1};
            *(uint32_t*)&G[(nt * 16 + ml) * GROW + 16 * wave + mt * 8 + 2 * q] = *(uint32_t*)p;
        }
    __syncthreads();

    {
        floatx4 sacc[2][4];
        #pragma unroll
        for (int mt = 0; mt < 2; ++mt)
            #pragma unroll
            for (int nt = 0; nt < 4; ++nt)
                #pragma unroll
                for (int r = 0; r < 4; ++r) sacc[mt][nt][r] = 0.0f;
        #pragma unroll
        for (int ks = 0; ks < 4; ++ks) {
            half8 a[2];
            #pragma unroll
            for (int mt = 0; mt < 2; ++mt)
                a[mt] = *(const half8*)&skw[((((2 * wave + mt) * 4) + ks) * 64 + lane) * 8];
            #pragma unroll
            for (int nt = 0; nt < 4; ++nt) {
                half8 b = *(const half8*)&G[(nt * 16 + ml) * GROW + ks * 32 + q * 8];
                #pragma unroll
                for (int mt = 0; mt < 2; ++mt)
                    sacc[mt][nt] = __builtin_amdgcn_mfma_f32_16x16x32_f16(a[mt], b, sacc[mt][nt], 0, 0, 0);
            }
        }
        _Float16* cp = chunk + ((size_t)n * NTB + tb) * 16384;
        #pragma unroll
        for (int mt = 0; mt < 2; ++mt)
            #pragma unroll
            for (int nt = 0; nt < 4; ++nt) {
                size_t o = (size_t)((((wave * 2 + mt) * 4) + nt) * 64 + lane) * 4;
                half4 v = *(const half4*)&cp[o];
                half4 w;
                #pragma unroll
                for (int r = 0; r < 4; ++r)
                    w[r] = (_Float16)(sacc[mt][nt][r] + (float)v[r]);
                *(half4*)&cp[o] = w;
            }
    }

    {
        floatx4 racc[4];
        #pragma unroll
        for (int r = 0; r < 4; ++r) {
            float bias = rb[16 * wave + q * 4 + r];
            #pragma unroll
            for (int nt = 0; nt < 4; ++nt) racc[nt][r] = bias;
        }
        #pragma unroll
        for (int ks = 0; ks < 4; ++ks) {
            half8 a = *(const half8*)&rsw[(((wave * 4) + ks) * 64 + lane) * 8];
            #pragma unroll
            for (int nt = 0; nt < 4; ++nt) {
                half8 b = *(const half8*)&G[(nt * 16 + ml) * GROW + ks * 32 + q * 8];
                racc[nt] = __builtin_amdgcn_mfma_f32_16x16x32_f16(a, b, racc[nt], 0, 0, 0);
            }
        }
        _Float16* ho = h_out + (size_t)n * WLEN * 128;
        #pragma unroll
        for (int nt = 0; nt < 4; ++nt) {
            int tt = nt * 16 + ml;
            int c = 16 * wave + q * 4;
            half4 hv = *(const half4*)&X1[tt * GROW + c];
            half4 o;
            #pragma unroll
            for (int r = 0; r < 4; ++r)
                o[r] = (_Float16)(racc[nt][r] + (float)hv[r]);
            *(half4*)&ho[(size_t)(t0 + tt) * 128 + c] = o;
        }
    }
}

// ---------------- head (round-7, 8 waves) ----------------
__global__ __launch_bounds__(512, 8) void head_kernel(
    float* __restrict__ out, const _Float16* __restrict__ chunk,
    const _Float16* __restrict__ aw, const float* __restrict__ ab,
    const _Float16* __restrict__ bw, const float* __restrict__ bb) {
    __shared__ _Float16 X[TT * XROW];
    const int n = blockIdx.y, tb = blockIdx.x, t0 = tb * TT;
    const int tid = threadIdx.x;
    const int wave = __builtin_amdgcn_readfirstlane(tid >> 6);
    const int lane = tid & 63, q = lane >> 4, ml = lane & 15;

    {
        const _Float16* cp = chunk + ((size_t)n * NTB + tb) * 16384;
        #pragma unroll
        for (int mt = 0; mt < 2; ++mt)
            #pragma unroll
            for (int nt = 0; nt < 4; ++nt) {
                size_t o = (size_t)((((wave * 2 + mt) * 4) + nt) * 64 + lane) * 4;
                half4 v = *(const half4*)&cp[o];
                half4 z;
                #pragma unroll
                for (int r = 0; r < 4; ++r)
                    z[r] = (_Float16)fmaxf((float)v[r], 0.0f);
                *(half4*)&X[(nt * 16 + ml) * XROW + 32 * wave + mt * 16 + q * 4] = z;
            }
    }
    __syncthreads();

    floatx4 acc[2][4];
    #pragma unroll
    for (int mt = 0; mt < 2; ++mt)
        #pragma unroll
        for (int r = 0; r < 4; ++r) {
            float bias = ab[32 * wave + mt * 16 + q * 4 + r];
            #pragma unroll
            for (int nt = 0; nt < 4; ++nt) acc[mt][nt][r] = bias;
        }
    for (int ks = 0; ks < 8; ++ks) {
        half8 a[2];
        #pragma unroll
        for (int mt = 0; mt < 2; ++mt)
            a[mt] = *(const half8*)&aw[((((2 * wave + mt) * 8) + ks) * 64 + lane) * 8];
        #pragma unroll
        for (int nt = 0; nt < 4; ++nt) {
            half8 b = *(const half8*)&X[(nt * 16 + ml) * XROW + ks * 32 + q * 8];
            #pragma unroll
            for (int mt = 0; mt < 2; ++mt)
                acc[mt][nt] = __builtin_amdgcn_mfma_f32_16x16x32_f16(a[mt], b, acc[mt][nt], 0, 0, 0);
        }
    }
    __syncthreads();
    #pragma unroll
    for (int mt = 0; mt < 2; ++mt)
        #pragma unroll
        for (int nt = 0; nt < 4; ++nt) {
            half4 z;
            #pragma unroll
            for (int r = 0; r < 4; ++r)
                z[r] = (_Float16)fmaxf(acc[mt][nt][r], 0.0f);
            *(half4*)&X[(nt * 16 + ml) * XROW + 32 * wave + mt * 16 + q * 4] = z;
        }
    __syncthreads();

    #pragma unroll
    for (int mt = 0; mt < 2; ++mt)
        #pragma unroll
        for (int r = 0; r < 4; ++r) {
            float bias = bb[32 * wave + mt * 16 + q * 4 + r];
            #pragma unroll
            for (int nt = 0; nt < 4; ++nt) acc[mt][nt][r] = bias;
        }
    for (int ks = 0; ks < 8; ++ks) {
        half8 a[2];
        #pragma unroll
        for (int mt = 0; mt < 2; ++mt)
            a[mt] = *(const half8*)&bw[((((2 * wave + mt) * 8) + ks) * 64 + lane) * 8];
        #pragma unroll
        for (int nt = 0; nt < 4; ++nt) {
            half8 b = *(const half8*)&X[(nt * 16 + ml) * XROW + ks * 32 + q * 8];
            #pragma unroll
            for (int mt = 0; mt < 2; ++mt)
                acc[mt][nt] = __builtin_amdgcn_mfma_f32_16x16x32_f16(a[mt], b, acc[mt][nt], 0, 0, 0);
        }
    }
    float* on = out + (size_t)n * S * WLEN;
    #pragma unroll
    for (int mt = 0; mt < 2; ++mt)
        #pragma unroll
        for (int nt = 0; nt < 4; ++nt)
            #pragma unroll
            for (int r = 0; r < 4; ++r) {
                int o = 32 * wave + mt * 16 + q * 4 + r;
                int tt = t0 + nt * 16 + ml;
                on[(size_t)o * WLEN + tt] = acc[mt][nt][r];
            }
}

extern "C" void kernel_launch(void* const* d_in, const int* in_sizes, int n_in,
                              void* d_out, int out_size, void* d_ws, size_t ws_size,
                              hipStream_t stream) {
    (void)in_sizes; (void)n_in; (void)out_size; (void)ws_size;
    const float* x       = (const float*)d_in[0];
    const float* w_shift = (const float*)d_in[1];
    const float* b_shift = (const float*)d_in[2];
    const float* conv_w  = (const float*)d_in[3];
    const float* conv_b  = (const float*)d_in[4];
    const float* res_w   = (const float*)d_in[5];
    const float* res_b   = (const float*)d_in[6];
    const float* skip_w  = (const float*)d_in[7];
    const float* skip_b  = (const float*)d_in[8];
    const float* a_w     = (const float*)d_in[9];
    const float* a_b     = (const float*)d_in[10];
    const float* b_w     = (const float*)d_in[11];
    const float* b_b     = (const float*)d_in[12];
    float* out = (float*)d_out;

    char* ws = (char*)d_ws;
    size_t off = 0;
    _Float16* hA    = (_Float16*)(ws + off); off += (size_t)NB * WLEN * 128 * 2;
    _Float16* hB    = (_Float16*)(ws + off); off += (size_t)NB * WLEN * 128 * 2;
    _Float16* chunk = (_Float16*)(ws + off); off += (size_t)NB * NTB * 16384 * 2;
    _Float16* cw  = (_Float16*)(ws + off); off += (size_t)NLAYERS * 256 * 256 * 2;
    _Float16* rsw = (_Float16*)(ws + off); off += (size_t)NLAYERS * 128 * 128 * 2;
    _Float16* skw = (_Float16*)(ws + off); off += (size_t)NLAYERS * 256 * 128 * 2;
    _Float16* aw  = (_Float16*)(ws + off); off += 256 * 256 * 2;
    _Float16* bw  = (_Float16*)(ws + off); off += 256 * 256 * 2;
    float* cbp  = (float*)(ws + off); off += (size_t)NLAYERS * 256 * 4;
    float* ssum = (float*)(ws + off); off += 256 * 4;
    // total ~74.3 MB

    prep_kernel<<<512, 256, 0, stream>>>(conv_w, res_w, skip_w, a_w, b_w,
                                         conv_b, skip_b,
                                         cw, rsw, skw, aw, bw, cbp, ssum);
    front_kernel<<<dim3(WLEN / 256, NB), 256, 0, stream>>>(x, w_shift, b_shift, hA);

    const dim3 grid(NTB, NB);
    _Float16* hin = hA;
    _Float16* hout = hB;
    for (int s = 0; s < 3; ++s) {
        const int l0 = s * 10;
        // stackA: layers l0..l0+3 (d=1,2,4,8), 80-row window
        if (s == 0)
            stack_kernel<0, 4, 5, 16, true><<<grid, 512, 0, stream>>>(
                hin, hout, chunk,
                cw + (size_t)l0 * 65536, cbp + l0 * 256,
                rsw + (size_t)l0 * 16384, res_b + l0 * 128,
                skw + (size_t)l0 * 32768, ssum);
        else
            stack_kernel<0, 4, 5, 16, false><<<grid, 512, 0, stream>>>(
                hin, hout, chunk,
                cw + (size_t)l0 * 65536, cbp + l0 * 256,
                rsw + (size_t)l0 * 16384, res_b + l0 * 128,
                skw + (size_t)l0 * 32768, ssum);
        { _Float16* tmp = hin; hin = hout; hout = tmp; }
        // single layers l0+4 .. l0+9 (d = 16..512)
        for (int jj = 4; jj < 10; ++jj) {
            const int l = l0 + jj;
            const int dil = 1 << jj;
            layer_kernel<<<grid, 512, 0, stream>>>(
                hin, hout, chunk,
                cw + (size_t)l * 65536, cbp + l * 256,
                rsw + (size_t)l * 16384, res_b + l * 128,
                skw + (size_t)l * 32768, dil);
            _Float16* tmp = hin; hin = hout; hout = tmp;
        }
    }

    head_kernel<<<grid, 512, 0, stream>>>(out, chunk, aw, a_b, bw, b_b);
}